// Round 9
// baseline (3809.598 us; speedup 1.0000x reference)
//
#include <hip/hip_runtime.h>

// ---------------------------------------------------------------------------
// EBMAttention (B=8, S=2048, E=1024, H=1), fp32 in/out.
// Round 9: occupancy push on the two non-image GEMMs: ring-2 LDS (48KB) ->
// 3 blocks/CU (24 waves/CU), launch_bounds(512,6).  gemm_e3 keeps the BK=16
// seg-interleaved 3-product body; gemm_big adopts the same double-barrier
// ring-2 shape.  Everything else identical to round 8.
// Math pipeline:
//   q_w = query @ P^T + c  (P = We@Wq),  k = key@Wk^T+bk,  v = value@Wv^T+bv
//   energy = q_w @ k^T; attn = softmax(-energy) (mask); out = attn @ v
// Pre-softmax GEMMs: 3-product hi/lo bf16 split (near-fp32 via MFMA).
// Operands are pre-tiled bf16 "LDS-images": per 128x32 tile, 16B chunk
// c = g*128 + r holds X[r][kt*32+g*8 .. +7].
// ---------------------------------------------------------------------------

typedef __attribute__((ext_vector_type(8))) short short8;
typedef __attribute__((ext_vector_type(4))) float f32x4;
typedef __attribute__((ext_vector_type(16))) float f32x16;

#define E_DIM 1024
#define S_LEN 2048
#define NB 8

// round-to-nearest-even fp32 -> bf16 bits
__device__ __forceinline__ unsigned short rne_bf(float x) {
    unsigned int u = __float_as_uint(x);
    return (unsigned short)((u + 0x7fffu + ((u >> 16) & 1u)) >> 16);
}

__device__ __forceinline__ void splitbf(float x, unsigned short& h, unsigned short& l) {
    unsigned int u = __float_as_uint(x);
    unsigned int rh = ((u + 0x7fffu + ((u >> 16) & 1u)) >> 16) << 16;
    h = (unsigned short)(rh >> 16);
    float r = x - __uint_as_float(rh);
    unsigned int v = __float_as_uint(r);
    l = (unsigned short)((v + 0x7fffu + ((v >> 16) & 1u)) >> 16);
}

__device__ __forceinline__ void lds_cp16(const void* g, void* l) {
    __builtin_amdgcn_global_load_lds(
        (const __attribute__((address_space(1))) unsigned int*)g,
        (__attribute__((address_space(3))) unsigned int*)l, 16, 0, 0);
}

__device__ __forceinline__ void wait_vm4() { asm volatile("s_waitcnt vmcnt(4)" ::: "memory"); }
__device__ __forceinline__ void wait_vm3() { asm volatile("s_waitcnt vmcnt(3)" ::: "memory"); }
__device__ __forceinline__ void wait_vm0() { asm volatile("s_waitcnt vmcnt(0)" ::: "memory"); }

// Bijective XCD-aware swizzle of (bx,by) within a z-plane.
__device__ __forceinline__ void swizzle_xy(int& bx, int& by) {
    const int gx = gridDim.x, gy = gridDim.y;
    const int nwg = gx * gy;
    const int w = by * gx + bx;
    if ((gx & 3) == 0 && (gy & 3) == 0 && (((gx >> 2) * (gy >> 2)) & 7) == 0) {
        const int nchx = gx >> 2;
        const int xcd = w & 7, i = w >> 3;
        const int j = i >> 4, p = i & 15;
        const int ch = xcd + 8 * j;
        const int chy = ch / nchx, chx = ch - chy * nchx;
        by = chy * 4 + (p >> 2);
        bx = chx * 4 + (p & 3);
    } else if ((nwg & 7) == 0) {
        const int cpx = nwg >> 3;
        const int sw = (w & 7) * cpx + (w >> 3);
        bx = sw % gx;
        by = sw / gx;
    }
}

// ---------------------------------------------------------------------------
// conv_img: fp32 [R x K] row-major -> h-image (+ l-image).  grid=(K/32, R/128)
// ---------------------------------------------------------------------------
template <bool DO_L>
__global__ __launch_bounds__(256) void conv_img(
    const float* __restrict__ src, unsigned short* __restrict__ h,
    unsigned short* __restrict__ l, int ld, int nkt)
{
    const int t = threadIdx.x;
    const long long tb = ((long long)blockIdx.y * nkt + blockIdx.x) * 4096;
    const float* s0 = src + (long long)blockIdx.y * 128 * ld + blockIdx.x * 32;
#pragma unroll
    for (int i = 0; i < 4; ++i) {
        const int f = i * 256 + t;
        const int r = f >> 3;
        const int c4 = (f & 7) << 2;
        const float4 v = *(const float4*)(s0 + (long long)r * ld + c4);
        const int gg = c4 >> 3;
        const int half = (c4 >> 2) & 1;
        const long long wo = tb + (long long)(gg * 128 + r) * 8 + half * 4;
        unsigned short h0, h1, h2, h3;
        if (DO_L) {
            unsigned short l0, l1, l2, l3;
            splitbf(v.x, h0, l0); splitbf(v.y, h1, l1);
            splitbf(v.z, h2, l2); splitbf(v.w, h3, l3);
            uint2 hp, lp;
            hp.x = h0 | ((unsigned)h1 << 16); hp.y = h2 | ((unsigned)h3 << 16);
            lp.x = l0 | ((unsigned)l1 << 16); lp.y = l2 | ((unsigned)l3 << 16);
            *(uint2*)(h + wo) = hp;
            *(uint2*)(l + wo) = lp;
        } else {
            h0 = rne_bf(v.x); h1 = rne_bf(v.y); h2 = rne_bf(v.z); h3 = rne_bf(v.w);
            uint2 hp;
            hp.x = h0 | ((unsigned)h1 << 16); hp.y = h2 | ((unsigned)h3 << 16);
            *(uint2*)(h + wo) = hp;
        }
    }
}

// ---------------------------------------------------------------------------
// conv_imgT: emit h+l images of src^T directly (src fp32 1024x1024).
// ---------------------------------------------------------------------------
__global__ __launch_bounds__(256) void conv_imgT(
    const float* __restrict__ src, unsigned short* __restrict__ h,
    unsigned short* __restrict__ l, int nkt)
{
    __shared__ float tile[32][132];
    const int t = threadIdx.x;
    const int kt = blockIdx.x;
    const int rb = blockIdx.y;
    const float* s0 = src + (long long)kt * 32 * E_DIM + rb * 128;
#pragma unroll
    for (int i = 0; i < 4; ++i) {
        const int f = i * 256 + t;
        const int r = f >> 5;
        const int c4 = (f & 31) << 2;
        const float4 v = *(const float4*)(s0 + (long long)r * E_DIM + c4);
        tile[r][c4] = v.x; tile[r][c4 + 1] = v.y;
        tile[r][c4 + 2] = v.z; tile[r][c4 + 3] = v.w;
    }
    __syncthreads();
    const long long tb = ((long long)rb * nkt + kt) * 4096;
#pragma unroll
    for (int i = 0; i < 2; ++i) {
        const int c = i * 256 + t;
        const int g = c >> 7, r = c & 127;
        unsigned short hh[8], ll[8];
#pragma unroll
        for (int j = 0; j < 8; ++j) splitbf(tile[g * 8 + j][r], hh[j], ll[j]);
        uint4 hp, lp;
        hp.x = hh[0] | ((unsigned)hh[1] << 16); hp.y = hh[2] | ((unsigned)hh[3] << 16);
        hp.z = hh[4] | ((unsigned)hh[5] << 16); hp.w = hh[6] | ((unsigned)hh[7] << 16);
        lp.x = ll[0] | ((unsigned)ll[1] << 16); lp.y = ll[2] | ((unsigned)ll[3] << 16);
        lp.z = ll[4] | ((unsigned)ll[5] << 16); lp.w = ll[6] | ((unsigned)ll[7] << 16);
        *(uint4*)(h + tb + (long long)c * 8) = hp;
        *(uint4*)(l + tb + (long long)c * 8) = lp;
    }
}

// ---------------------------------------------------------------------------
// gemm_e3: energy GEMM, seg-interleaved 3-product split.
// 256x128 tile, BK=16, 8 waves (wave tile 64x64 = 2x2 of 32x32 MFMA).
// Ring-2 x 24KB buffers (48KB LDS) -> 3 blocks/CU; double-barrier loop.
// ---------------------------------------------------------------------------
__global__ __launch_bounds__(512, 6) void gemm_e3(
    const unsigned short* __restrict__ Ah, const unsigned short* __restrict__ Al,
    const unsigned short* __restrict__ Bh, const unsigned short* __restrict__ Bl,
    float* __restrict__ C, int ldC, long long bsC, int nkt32, int aZrb, int bZrb)
{
    __shared__ unsigned short smb[24576];   // 2 x 24KB

    const int t = threadIdx.x;
    const int wv = t >> 6, lane = t & 63;
    const int wr = wv >> 1, wc = wv & 1;
    const int l31 = lane & 31, lh = lane >> 5;

    int bx = blockIdx.x, by = blockIdx.y;
    swizzle_xy(bx, by);

    const long long aB0 = ((long long)blockIdx.z * aZrb + 2 * by) * nkt32 * 4096;
    const long long aB1 = aB0 + (long long)nkt32 * 4096;
    const long long bB0 = ((long long)blockIdx.z * bZrb + bx) * nkt32 * 4096;

    const int rA = t & 255, glA = t >> 8;
    const int bc = t & 255;
    auto stage = [&](int k16, int c) {
        unsigned short* buf = smb + c * 12288;
        const int kt32 = k16 >> 1, hh = k16 & 1;
        const long long aOff = ((rA >> 7) ? aB1 : aB0) + (long long)kt32 * 4096
                             + ((2 * hh + glA) * 128 + (rA & 127)) * 8;
        lds_cp16(Ah + aOff, buf + t * 8);
        lds_cp16(Al + aOff, buf + 4096 + t * 8);
        const long long bOff = bB0 + (long long)kt32 * 4096
                             + ((2 * hh + (bc >> 7)) * 128 + (bc & 127)) * 8;
        const unsigned short* bsrc = (t < 256) ? Bh : Bl;   // wave-uniform
        lds_cp16(bsrc + bOff, buf + 8192 + t * 8);
    };

    short8 ah[2], al[2], bh[2], bl[2];
    auto loadFrags = [&](int c) {
        const unsigned short* buf = smb + c * 12288;
#pragma unroll
        for (int m = 0; m < 2; ++m) {
            const int ra = lh * 256 + wr * 64 + m * 32 + l31;
            ah[m] = *(const short8*)(buf + ra * 8);
            al[m] = *(const short8*)(buf + 4096 + ra * 8);
        }
#pragma unroll
        for (int n = 0; n < 2; ++n) {
            const int rb = lh * 128 + wc * 64 + n * 32 + l31;
            bh[n] = *(const short8*)(buf + 8192 + rb * 8);
            bl[n] = *(const short8*)(buf + 10240 + rb * 8);
        }
    };

    f32x16 acc[2][2] = {};
    const int n16 = nkt32 * 2;

    stage(0, 0);

    for (int s = 0; s < n16; ++s) {
        __builtin_amdgcn_s_barrier();           // all waves done reading buf[(s-1)&1]
        if (s + 1 < n16) {
            stage(s + 1, (s + 1) & 1);
            wait_vm3();                          // own stage(s) landed
        } else {
            wait_vm0();
        }
        __builtin_amdgcn_s_barrier();           // all waves' stage(s) landed
        __builtin_amdgcn_sched_barrier(0);
        loadFrags(s & 1);
        __builtin_amdgcn_s_setprio(1);
#pragma unroll
        for (int m = 0; m < 2; ++m)
#pragma unroll
            for (int n = 0; n < 2; ++n)
                acc[m][n] = __builtin_amdgcn_mfma_f32_32x32x16_bf16(ah[m], bh[n], acc[m][n], 0, 0, 0);
#pragma unroll
        for (int m = 0; m < 2; ++m)
#pragma unroll
            for (int n = 0; n < 2; ++n)
                acc[m][n] = __builtin_amdgcn_mfma_f32_32x32x16_bf16(al[m], bh[n], acc[m][n], 0, 0, 0);
#pragma unroll
        for (int m = 0; m < 2; ++m)
#pragma unroll
            for (int n = 0; n < 2; ++n)
                acc[m][n] = __builtin_amdgcn_mfma_f32_32x32x16_bf16(ah[m], bl[n], acc[m][n], 0, 0, 0);
        __builtin_amdgcn_s_setprio(0);
    }

    // 32x32 C/D layout: col = lane&31, row = (reg&3) + 8*(reg>>2) + 4*(lane>>5)
    float* Cb = C + (long long)blockIdx.z * bsC;
#pragma unroll
    for (int m = 0; m < 2; ++m)
#pragma unroll
        for (int n = 0; n < 2; ++n) {
            const int gc = bx * 128 + wc * 64 + n * 32 + l31;
            const int gr0 = by * 256 + wr * 64 + m * 32 + 4 * lh;
#pragma unroll
            for (int reg = 0; reg < 16; ++reg) {
                const int row = (reg & 3) + 8 * (reg >> 2);
                Cb[(long long)(gr0 + row) * ldC + gc] = acc[m][n][reg];
            }
        }
}

// ---------------------------------------------------------------------------
// gemm_big: 256x128 tile, 8 waves — out-GEMM (NPROD=1).
// Ring-2 x 24KB (48KB LDS) -> 3 blocks/CU; double-barrier loop.
// ---------------------------------------------------------------------------
template <int NPROD>
__global__ __launch_bounds__(512, 6) void gemm_big(
    const unsigned short* __restrict__ Ah, const unsigned short* __restrict__ Al,
    const unsigned short* __restrict__ Bh, const unsigned short* __restrict__ Bl,
    float* __restrict__ C, const float* __restrict__ bias,
    int ldC, long long bsC, int nkt, int aZrb, int bZrb)
{
    __shared__ unsigned short smb[24576];   // 2 x 24KB

    const int t = threadIdx.x;
    const int wv = t >> 6, lane = t & 63;
    const int wr = wv >> 1, wc = wv & 1;
    const int lr = lane & 15, gq = lane >> 4;

    int bx = blockIdx.x, by = blockIdx.y;
    swizzle_xy(bx, by);

    const long long aB0 = ((long long)blockIdx.z * aZrb + 2 * by) * nkt * 4096;
    const long long aB1 = aB0 + (long long)nkt * 4096;
    const long long bB0 = ((long long)blockIdx.z * bZrb + bx) * nkt * 4096;

    auto srcptr = [&](int s, const unsigned short*& a0, const unsigned short*& a1,
                      const unsigned short*& bS) {
        int seg, kt;
        if (NPROD == 3) {
            seg = (s >= 2 * nkt) ? 2 : (s >= nkt ? 1 : 0);
            kt = s - seg * nkt;
        } else { seg = 0; kt = s; }
        const unsigned short* aBase = ((NPROD == 3 && seg == 1) ? Al : Ah);
        const unsigned short* bBase = ((NPROD == 3 && seg == 2) ? Bl : Bh);
        a0 = aBase + aB0 + (long long)kt * 4096;
        a1 = aBase + aB1 + (long long)kt * 4096;
        bS = bBase + bB0 + (long long)kt * 4096;
    };
    auto stage = [&](const unsigned short* a0, const unsigned short* a1,
                     const unsigned short* bS, int c) {
        unsigned short* dA = smb + c * 12288;
        lds_cp16(a0 + t * 8, dA + t * 8);
        lds_cp16(a1 + t * 8, dA + 4096 + t * 8);
        lds_cp16(bS + t * 8, dA + 8192 + t * 8);
    };

    short8 af[4], bfr[4];
    auto loadFrags = [&](int c) {
        const unsigned short* dA = smb + c * 12288;
        const unsigned short* dB = dA + 8192;
#pragma unroll
        for (int m = 0; m < 4; ++m) {
            const int R = wr * 64 + m * 16 + lr;
            af[m] = *(const short8*)(dA + (R >> 7) * 4096 + (gq * 128 + (R & 127)) * 8);
        }
#pragma unroll
        for (int n = 0; n < 4; ++n) {
            const int Cc = wc * 64 + n * 16 + lr;
            bfr[n] = *(const short8*)(dB + (gq * 128 + Cc) * 8);
        }
    };

    f32x4 acc[4][4] = {};
    const int nsteps = NPROD * nkt;

    {
        const unsigned short *a0, *a1, *bS;
        srcptr(0, a0, a1, bS); stage(a0, a1, bS, 0);
    }

    for (int s = 0; s < nsteps; ++s) {
        __builtin_amdgcn_s_barrier();
        if (s + 1 < nsteps) {
            const unsigned short *a0, *a1, *bS;
            srcptr(s + 1, a0, a1, bS);
            stage(a0, a1, bS, (s + 1) & 1);
            wait_vm3();
        } else {
            wait_vm0();
        }
        __builtin_amdgcn_s_barrier();
        __builtin_amdgcn_sched_barrier(0);
        loadFrags(s & 1);
        __builtin_amdgcn_s_setprio(1);
#pragma unroll
        for (int m = 0; m < 4; ++m)
#pragma unroll
            for (int n = 0; n < 4; ++n)
                acc[m][n] = __builtin_amdgcn_mfma_f32_16x16x32_bf16(af[m], bfr[n], acc[m][n], 0, 0, 0);
        __builtin_amdgcn_s_setprio(0);
    }

    const int cr = (lane >> 4) << 2, cc = lane & 15;
    float* Cb = C + (long long)blockIdx.z * bsC;
#pragma unroll
    for (int m = 0; m < 4; ++m)
#pragma unroll
        for (int n = 0; n < 4; ++n) {
            const int gc = bx * 128 + wc * 64 + n * 16 + cc;
            const float badd = bias ? bias[gc] : 0.0f;
            const int gr0 = by * 256 + wr * 64 + m * 16 + cr;
#pragma unroll
            for (int i = 0; i < 4; ++i)
                Cb[(long long)(gr0 + i) * ldC + gc] = acc[m][n][i] + badd;
        }
}

// ---------------------------------------------------------------------------
// gemm_img: 128x128, 4 waves — image-emitting variants (WMODE 1 / 3).
// Round-7 structure (unchanged).  Dyn LDS 49152 B (already 3 blocks/CU).
// ---------------------------------------------------------------------------
template <int NPROD, int WMODE>
__global__ __launch_bounds__(256) void gemm_img(
    const unsigned short* __restrict__ Ah, const unsigned short* __restrict__ Al,
    const unsigned short* __restrict__ Bh, const unsigned short* __restrict__ Bl,
    float* __restrict__ C, const float* __restrict__ bias,
    unsigned short* __restrict__ imgH, unsigned short* __restrict__ imgL,
    int ldC, long long bsC, int nkt, int aZrb, int bZrb, int outNkt)
{
    extern __shared__ unsigned short sm[];

    const int t = threadIdx.x;
    const int wv = t >> 6, lane = t & 63;
    const int wm = (wv >> 1) << 6, wn = (wv & 1) << 6;
    const int lr = lane & 15, gq = lane >> 4;

    int bx = blockIdx.x, by = blockIdx.y;
    swizzle_xy(bx, by);

    const long long aB0 = ((long long)blockIdx.z * aZrb + by) * nkt * 4096;
    const long long bB0 = ((long long)blockIdx.z * bZrb + bx) * nkt * 4096;

    auto srcptr = [&](int s, const unsigned short*& aS, const unsigned short*& bS) {
        int seg, kt;
        if (NPROD == 3) {
            seg = (s >= 2 * nkt) ? 2 : (s >= nkt ? 1 : 0);
            kt = s - seg * nkt;
        } else { seg = 0; kt = s; }
        aS = ((NPROD == 3 && seg == 1) ? Al : Ah) + aB0 + (long long)kt * 4096;
        bS = ((NPROD == 3 && seg == 2) ? Bl : Bh) + bB0 + (long long)kt * 4096;
    };
    auto stage = [&](const unsigned short* aS, const unsigned short* bS, int c) {
        unsigned short* dA = sm + c * 8192;
        unsigned short* dB = dA + 4096;
#pragma unroll
        for (int j = 0; j < 2; ++j) {
            lds_cp16(aS + (wv * 128 + j * 64 + lane) * 8, dA + (wv * 128 + j * 64) * 8);
            lds_cp16(bS + (wv * 128 + j * 64 + lane) * 8, dB + (wv * 128 + j * 64) * 8);
        }
    };

    short8 af[4], bfr[4];
    auto loadFrags = [&](int c) {
        const unsigned short* smA = sm + c * 8192;
        const unsigned short* smB = smA + 4096;
        const unsigned short* pa = smA + (gq * 128 + wm + lr) * 8;
        const unsigned short* pb = smB + (gq * 128 + wn + lr) * 8;
#pragma unroll
        for (int m = 0; m < 4; ++m) af[m] = *(const short8*)(pa + m * 128);
#pragma unroll
        for (int n = 0; n < 4; ++n) bfr[n] = *(const short8*)(pb + n * 128);
    };

    f32x4 acc[4][4] = {};
    const int nsteps = NPROD * nkt;

    {
        const unsigned short *aS, *bS;
        srcptr(0, aS, bS); stage(aS, bS, 0);
        srcptr(1, aS, bS); stage(aS, bS, 1);
    }
    wait_vm4();
    __builtin_amdgcn_s_barrier();
    __builtin_amdgcn_sched_barrier(0);
    loadFrags(0);

    for (int s = 0; s < nsteps; ++s) {
        if (s + 2 < nsteps) {
            const unsigned short *aS, *bS;
            srcptr(s + 2, aS, bS);
            stage(aS, bS, (s + 2) % 3);
        }
        __builtin_amdgcn_sched_barrier(0);
        __builtin_amdgcn_s_setprio(1);
#pragma unroll
        for (int m = 0; m < 4; ++m)
#pragma unroll
            for (int n = 0; n < 4; ++n)
                acc[m][n] = __builtin_amdgcn_mfma_f32_16x16x32_bf16(af[m], bfr[n], acc[m][n], 0, 0, 0);
        __builtin_amdgcn_s_setprio(0);
        __builtin_amdgcn_sched_barrier(0);
        if (s + 1 < nsteps) {
            if (s + 2 < nsteps) wait_vm4();
            else wait_vm0();
            __builtin_amdgcn_s_barrier();
            __builtin_amdgcn_sched_barrier(0);
            loadFrags((s + 1) % 3);
        }
    }

    const int cr = (lane >> 4) << 2, cc = lane & 15;
    if (WMODE == 0) {
        float* Cb = C + (long long)blockIdx.z * bsC;
#pragma unroll
        for (int m = 0; m < 4; ++m)
#pragma unroll
            for (int n = 0; n < 4; ++n) {
                const int gc = bx * 128 + wn + n * 16 + cc;
                const float badd = bias ? bias[gc] : 0.0f;
                const int gr0 = by * 128 + wm + m * 16 + cr;
#pragma unroll
                for (int i = 0; i < 4; ++i)
                    Cb[(long long)(gr0 + i) * ldC + gc] = acc[m][n][i] + badd;
            }
    } else {
        float* slab = (float*)sm;   // [2][16][132] fp32
        const int wmi = wv >> 1;
#pragma unroll
        for (int m = 0; m < 4; ++m) {
            __syncthreads();
#pragma unroll
            for (int n = 0; n < 4; ++n) {
                const int col = wn + n * 16 + cc;
                const float badd = bias ? bias[bx * 128 + col] : 0.0f;
#pragma unroll
                for (int i = 0; i < 4; ++i)
                    slab[(wmi * 16 + cr + i) * 132 + col] = acc[m][n][i] + badd;
            }
            __syncthreads();
            if (WMODE == 1) {
#pragma unroll
                for (int it = 0; it < 2; ++it) {
                    const int e = it * 256 + t;
                    const int wq = e >> 8, cg = (e >> 4) & 15, fr = e & 15;
                    const float* sp = slab + (wq * 16 + fr) * 132 + cg * 8;
                    const int rIn = wq * 64 + m * 16 + fr;
                    const int ktO = bx * 4 + (cg >> 2);
                    const int gO = cg & 3;
                    const long long base =
                        ((long long)by * outNkt + ktO) * 4096 + (gO * 128 + rIn) * 8;
                    unsigned short h[8], l[8];
#pragma unroll
                    for (int j = 0; j < 8; ++j) splitbf(sp[j], h[j], l[j]);
                    uint4 hp, lp;
                    hp.x = h[0] | ((unsigned)h[1] << 16); hp.y = h[2] | ((unsigned)h[3] << 16);
                    hp.z = h[4] | ((unsigned)h[5] << 16); hp.w = h[6] | ((unsigned)h[7] << 16);
                    lp.x = l[0] | ((unsigned)l[1] << 16); lp.y = l[2] | ((unsigned)l[3] << 16);
                    lp.z = l[4] | ((unsigned)l[5] << 16); lp.w = l[6] | ((unsigned)l[7] << 16);
                    *(uint4*)(imgH + base) = hp;
                    *(uint4*)(imgL + base) = lp;
                }
            } else {    // WMODE 3: vT image (B-layout over C^T), h only
#pragma unroll
                for (int it = 0; it < 2; ++it) {
                    const int e = it * 256 + t;
                    const int wq = e >> 8, s8 = (e >> 7) & 1, dl = e & 127;
                    const int sG = by * 128 + wq * 64 + m * 16 + s8 * 8;
                    const int z = sG >> 11, sIn = sG & 2047;
                    const int ktO = sIn >> 5, gO = (sIn >> 3) & 3;
                    const long long base =
                        ((long long)(z * 8 + bx) * 64 + ktO) * 4096 + (gO * 128 + dl) * 8;
                    unsigned short h[8];
#pragma unroll
                    for (int j = 0; j < 8; ++j)
                        h[j] = rne_bf(slab[(wq * 16 + s8 * 8 + j) * 132 + dl]);
                    uint4 hp;
                    hp.x = h[0] | ((unsigned)h[1] << 16); hp.y = h[2] | ((unsigned)h[3] << 16);
                    hp.z = h[4] | ((unsigned)h[5] << 16); hp.w = h[6] | ((unsigned)h[7] << 16);
                    *(uint4*)(imgH + base) = hp;
                }
            }
        }
    }
}

// ---------------------------------------------------------------------------
// softmax over rows of energy, in place; also emits bf16 A-image of attn.
// ---------------------------------------------------------------------------
__global__ __launch_bounds__(256) void softmax_img(
    float* __restrict__ attn, const int* __restrict__ mask,
    unsigned short* __restrict__ img)
{
    const int row = blockIdx.x;
    const int q = row & (S_LEN - 1);
    const int t = threadIdx.x;
    const int lane = t & 63, wid = t >> 6;
    float* rp = attn + (long long)row * S_LEN;
    const int* mp = mask + (long long)q * S_LEN;

    const float4 e0 = *(const float4*)(rp + t * 8);
    const float4 e1 = *(const float4*)(rp + t * 8 + 4);
    const int4 ma = *(const int4*)(mp + t * 8);
    const int4 mb = *(const int4*)(mp + t * 8 + 4);
    float zv[8];
    zv[0] = ma.x ? -e0.x : 1e9f;
    zv[1] = ma.y ? -e0.y : 1e9f;
    zv[2] = ma.z ? -e0.z : 1e9f;
    zv[3] = ma.w ? -e0.w : 1e9f;
    zv[4] = mb.x ? -e1.x : 1e9f;
    zv[5] = mb.y ? -e1.y : 1e9f;
    zv[6] = mb.z ? -e1.z : 1e9f;
    zv[7] = mb.w ? -e1.w : 1e9f;
    float mx = zv[0];
#pragma unroll
    for (int j = 1; j < 8; ++j) mx = fmaxf(mx, zv[j]);
#pragma unroll
    for (int o = 32; o > 0; o >>= 1) mx = fmaxf(mx, __shfl_xor(mx, o));
    __shared__ float redm[4], reds[4];
    if (lane == 0) redm[wid] = mx;
    __syncthreads();
    mx = fmaxf(fmaxf(redm[0], redm[1]), fmaxf(redm[2], redm[3]));
    float s = 0.f;
#pragma unroll
    for (int j = 0; j < 8; ++j) { zv[j] = expf(zv[j] - mx); s += zv[j]; }
#pragma unroll
    for (int o = 32; o > 0; o >>= 1) s += __shfl_xor(s, o);
    if (lane == 0) reds[wid] = s;
    __syncthreads();
    s = reds[0] + reds[1] + reds[2] + reds[3];
    const float inv = 1.0f / s;
    float4 o0, o1;
    o0.x = zv[0] * inv; o0.y = zv[1] * inv; o0.z = zv[2] * inv; o0.w = zv[3] * inv;
    o1.x = zv[4] * inv; o1.y = zv[5] * inv; o1.z = zv[6] * inv; o1.w = zv[7] * inv;
    *(float4*)(rp + t * 8) = o0;
    *(float4*)(rp + t * 8 + 4) = o1;
    const int z = row >> 11, rb = (row >> 7) & 15;
    const int ktO = t >> 2, gO = t & 3, r = row & 127;
    const long long base = (((long long)(z * 16 + rb) * 64 + ktO) * 512 + gO * 128 + r) * 8;
    uint4 hp;
    hp.x = rne_bf(o0.x) | ((unsigned)rne_bf(o0.y) << 16);
    hp.y = rne_bf(o0.z) | ((unsigned)rne_bf(o0.w) << 16);
    hp.z = rne_bf(o1.x) | ((unsigned)rne_bf(o1.y) << 16);
    hp.w = rne_bf(o1.z) | ((unsigned)rne_bf(o1.w) << 16);
    *(uint4*)(img + base) = hp;
}

// WqT[j][i] = Wq[i][j]  (1024x1024) — fallback path only
__global__ void transpose1024(const float* __restrict__ in, float* __restrict__ out)
{
    __shared__ float tile[32][33];
    const int bx = blockIdx.x << 5, by = blockIdx.y << 5;
    const int tx = threadIdx.x, ty = threadIdx.y;
#pragma unroll
    for (int i = 0; i < 4; ++i)
        tile[ty + 8 * i][tx] = in[(long long)(by + ty + 8 * i) * E_DIM + bx + tx];
    __syncthreads();
#pragma unroll
    for (int i = 0; i < 4; ++i)
        out[(long long)(bx + ty + 8 * i) * E_DIM + by + tx] = tile[tx][ty + 8 * i];
}

// c[i] = dot(bq, W_e[i,:])
__global__ __launch_bounds__(256) void bias_c_kernel(
    const float* __restrict__ We, const float* __restrict__ bq, float* __restrict__ c)
{
    const int i = blockIdx.x;
    const int t = threadIdx.x;
    float s = 0.f;
    for (int d = t; d < E_DIM; d += 256) s += bq[d] * We[(long long)i * E_DIM + d];
#pragma unroll
    for (int o = 32; o > 0; o >>= 1) s += __shfl_xor(s, o);
    __shared__ float red[4];
    if ((t & 63) == 0) red[t >> 6] = s;
    __syncthreads();
    if (t == 0) c[i] = red[0] + red[1] + red[2] + red[3];
}

// ---------------------------------------------------------------------------
// FALLBACK path (round-1 proven), used only if ws_size is too small.
// ---------------------------------------------------------------------------
template <bool SPLIT, int WMODE>
__global__ __launch_bounds__(256) void gemm_split(
    const float* __restrict__ A, const float* __restrict__ B,
    float* __restrict__ C, const float* __restrict__ bias,
    int M, int N, int K,
    long long bsA, long long bsB, long long bsC)
{
    extern __shared__ unsigned short sm[];
    unsigned short* sAh = sm;
    unsigned short* sBh = sm + 5120;
    unsigned short* sAl = sm + 10240;
    unsigned short* sBl = sm + 15360;

    const int t = threadIdx.x;
    const int z = blockIdx.z;
    const float* Ab = A + (long long)z * bsA + (long long)blockIdx.y * 128 * K;
    const float* Bb = B + (long long)z * bsB + (long long)blockIdx.x * 128 * K;

    const int wv = t >> 6;
    const int lane = t & 63;
    const int wm = (wv >> 1) << 6;
    const int wn = (wv & 1) << 6;
    const int lr = lane & 15;
    const int ko = (lane >> 4) << 3;

    f32x4 acc[4][4] = {};

    for (int k0 = 0; k0 < K; k0 += 32) {
        __syncthreads();
#pragma unroll
        for (int i = 0; i < 4; ++i) {
            const int f = t + (i << 8);
            const int row = f >> 3;
            const int c4 = (f & 7) << 2;
            const float4 av = *(const float4*)(Ab + (long long)row * K + k0 + c4);
            const float4 bv = *(const float4*)(Bb + (long long)row * K + k0 + c4);
            if (SPLIT) {
                unsigned short h0, h1, h2, h3, l0, l1, l2, l3;
                splitbf(av.x, h0, l0); splitbf(av.y, h1, l1);
                splitbf(av.z, h2, l2); splitbf(av.w, h3, l3);
                uint2 hp, lp;
                hp.x = (unsigned)h0 | ((unsigned)h1 << 16);
                hp.y = (unsigned)h2 | ((unsigned)h3 << 16);
                lp.x = (unsigned)l0 | ((unsigned)l1 << 16);
                lp.y = (unsigned)l2 | ((unsigned)l3 << 16);
                *(uint2*)(sAh + row * 40 + c4) = hp;
                *(uint2*)(sAl + row * 40 + c4) = lp;
                splitbf(bv.x, h0, l0); splitbf(bv.y, h1, l1);
                splitbf(bv.z, h2, l2); splitbf(bv.w, h3, l3);
                hp.x = (unsigned)h0 | ((unsigned)h1 << 16);
                hp.y = (unsigned)h2 | ((unsigned)h3 << 16);
                lp.x = (unsigned)l0 | ((unsigned)l1 << 16);
                lp.y = (unsigned)l2 | ((unsigned)l3 << 16);
                *(uint2*)(sBh + row * 40 + c4) = hp;
                *(uint2*)(sBl + row * 40 + c4) = lp;
            } else {
                uint2 hp;
                hp.x = (unsigned)rne_bf(av.x) | ((unsigned)rne_bf(av.y) << 16);
                hp.y = (unsigned)rne_bf(av.z) | ((unsigned)rne_bf(av.w) << 16);
                *(uint2*)(sAh + row * 40 + c4) = hp;
                hp.x = (unsigned)rne_bf(bv.x) | ((unsigned)rne_bf(bv.y) << 16);
                hp.y = (unsigned)rne_bf(bv.z) | ((unsigned)rne_bf(bv.w) << 16);
                *(uint2*)(sBh + row * 40 + c4) = hp;
            }
        }
        __syncthreads();
        short8 ah[4], bh[4], al[4], bl[4];
#pragma unroll
        for (int m = 0; m < 4; ++m)
            ah[m] = *(const short8*)(sAh + (wm + m * 16 + lr) * 40 + ko);
#pragma unroll
        for (int n = 0; n < 4; ++n)
            bh[n] = *(const short8*)(sBh + (wn + n * 16 + lr) * 40 + ko);
        if (SPLIT) {
#pragma unroll
            for (int m = 0; m < 4; ++m)
                al[m] = *(const short8*)(sAl + (wm + m * 16 + lr) * 40 + ko);
#pragma unroll
            for (int n = 0; n < 4; ++n)
                bl[n] = *(const short8*)(sBl + (wn + n * 16 + lr) * 40 + ko);
        }
#pragma unroll
        for (int m = 0; m < 4; ++m) {
#pragma unroll
            for (int n = 0; n < 4; ++n) {
                acc[m][n] = __builtin_amdgcn_mfma_f32_16x16x32_bf16(ah[m], bh[n], acc[m][n], 0, 0, 0);
                if (SPLIT) {
                    acc[m][n] = __builtin_amdgcn_mfma_f32_16x16x32_bf16(ah[m], bl[n], acc[m][n], 0, 0, 0);
                    acc[m][n] = __builtin_amdgcn_mfma_f32_16x16x32_bf16(al[m], bh[n], acc[m][n], 0, 0, 0);
                }
            }
        }
    }

    const int cr = (lane >> 4) << 2;
    const int cc = lane & 15;
    float* Cb = C + (long long)z * bsC;
#pragma unroll
    for (int m = 0; m < 4; ++m) {
#pragma unroll
        for (int n = 0; n < 4; ++n) {
            const int gc = blockIdx.x * 128 + wn + n * 16 + cc;
            const float badd = bias ? bias[gc] : 0.0f;
            const int gr0 = blockIdx.y * 128 + wm + m * 16 + cr;
#pragma unroll
            for (int i = 0; i < 4; ++i) {
                const float val = acc[m][n][i] + badd;
                if (WMODE == 0) {
                    Cb[(long long)(gr0 + i) * N + gc] = val;
                } else {
                    const int r = gr0 + i;
                    Cb[(long long)(r >> 11) * ((long long)N * 2048) +
                       (long long)gc * 2048 + (r & 2047)] = val;
                }
            }
        }
    }
}

__global__ __launch_bounds__(256) void softmax_rows(
    float* __restrict__ attn, const int* __restrict__ mask)
{
    const int row = blockIdx.x;
    const int q = row & (S_LEN - 1);
    const int t = threadIdx.x;
    const int lane = t & 63, wid = t >> 6;
    float* rp = attn + (long long)row * S_LEN;
    const int* mp = mask + (long long)q * S_LEN;

    float zv[8];
    float mx = -3.4e38f;
#pragma unroll
    for (int j = 0; j < 8; ++j) {
        const int idx = t + (j << 8);
        const float e = rp[idx];
        const int mv = mp[idx];
        const float zz = (mv != 0) ? -e : 1e9f;
        zv[j] = zz;
        mx = fmaxf(mx, zz);
    }
#pragma unroll
    for (int o = 32; o > 0; o >>= 1) mx = fmaxf(mx, __shfl_xor(mx, o));
    __shared__ float redm[4], reds[4];
    if (lane == 0) redm[wid] = mx;
    __syncthreads();
    mx = fmaxf(fmaxf(redm[0], redm[1]), fmaxf(redm[2], redm[3]));

    float s = 0.f;
#pragma unroll
    for (int j = 0; j < 8; ++j) { zv[j] = expf(zv[j] - mx); s += zv[j]; }
#pragma unroll
    for (int o = 32; o > 0; o >>= 1) s += __shfl_xor(s, o);
    if (lane == 0) reds[wid] = s;
    __syncthreads();
    s = reds[0] + reds[1] + reds[2] + reds[3];
    const float inv = 1.0f / s;
#pragma unroll
    for (int j = 0; j < 8; ++j) rp[t + (j << 8)] = zv[j] * inv;
}

// ---------------------------------------------------------------------------
extern "C" void kernel_launch(void* const* d_in, const int* in_sizes, int n_in,
                              void* d_out, int out_size, void* d_ws, size_t ws_size,
                              hipStream_t stream)
{
    const float* query = (const float*)d_in[0];
    const float* key   = (const float*)d_in[1];
    const float* value = (const float*)d_in[2];
    const int*   mask  = (const int*)d_in[3];
    const float* Wq    = (const float*)d_in[4];
    const float* bq    = (const float*)d_in[5];
    const float* Wk    = (const float*)d_in[6];
    const float* bk    = (const float*)d_in[7];
    const float* Wv    = (const float*)d_in[8];
    const float* bv    = (const float*)d_in[9];
    const float* We    = (const float*)d_in[10];

    float* out  = (float*)d_out;
    float* attn = out + (long long)NB * S_LEN * E_DIM;

    // ---------------- ws layout (byte offsets) ----------------
    const size_t oWqT  = 0;
    const size_t oCvec = oWqT + (4u << 20);
    const size_t oWqTH = oCvec + 4096;
    const size_t oWqTL = oWqTH + (2u << 20);
    const size_t oWeH  = oWqTL + (2u << 20);
    const size_t oWeL  = oWeH + (2u << 20);
    const size_t oWkH  = oWeL + (2u << 20);
    const size_t oWkL  = oWkH + (2u << 20);
    const size_t oWvH  = oWkL + (2u << 20);
    const size_t oPH   = oWvH + (2u << 20);
    const size_t oPL   = oPH + (2u << 20);
    const size_t oBig1 = oPL + (2u << 20);
    const size_t oBig2 = oBig1 + (64u << 20);
    const size_t oBig3 = oBig2 + (64u << 20);
    const size_t NEED  = oBig3 + (64u << 20);

    char* wsb = (char*)d_ws;

    if (ws_size >= NEED) {
        float* cvec = (float*)(wsb + oCvec);
        unsigned short* WqTH = (unsigned short*)(wsb + oWqTH);
        unsigned short* WqTL = (unsigned short*)(wsb + oWqTL);
        unsigned short* WeH  = (unsigned short*)(wsb + oWeH);
        unsigned short* WeL  = (unsigned short*)(wsb + oWeL);
        unsigned short* WkH  = (unsigned short*)(wsb + oWkH);
        unsigned short* WkL  = (unsigned short*)(wsb + oWkL);
        unsigned short* WvH  = (unsigned short*)(wsb + oWvH);
        unsigned short* PH   = (unsigned short*)(wsb + oPH);
        unsigned short* PL   = (unsigned short*)(wsb + oPL);
        unsigned short* qryH = (unsigned short*)(wsb + oBig1);
        unsigned short* qryL = (unsigned short*)(wsb + oBig1 + (32u << 20));
        unsigned short* attnH = (unsigned short*)(wsb + oBig1);           // alias
        unsigned short* keyH = (unsigned short*)(wsb + oBig2);
        unsigned short* keyL = (unsigned short*)(wsb + oBig2 + (32u << 20));
        unsigned short* qwH  = (unsigned short*)(wsb + oBig2);            // alias
        unsigned short* qwL  = (unsigned short*)(wsb + oBig2 + (32u << 20));
        unsigned short* kH   = (unsigned short*)(wsb + oBig3);
        unsigned short* kL   = (unsigned short*)(wsb + oBig3 + (32u << 20));
        unsigned short* vTH  = (unsigned short*)(wsb + oBig3);            // alias
        unsigned short* valH = (unsigned short*)(wsb + oBig3 + (32u << 20));

        bias_c_kernel<<<1024, 256, 0, stream>>>(We, bq, cvec);
        conv_imgT<<<dim3(32, 8), 256, 0, stream>>>(Wq, WqTH, WqTL, 32);
        conv_img<true><<<dim3(32, 8), 256, 0, stream>>>(We, WeH, WeL, 1024, 32);
        conv_img<true><<<dim3(32, 8), 256, 0, stream>>>(Wk, WkH, WkL, 1024, 32);
        conv_img<false><<<dim3(32, 8), 256, 0, stream>>>(Wv, WvH, nullptr, 1024, 32);
        conv_img<true><<<dim3(32, 128), 256, 0, stream>>>(query, qryH, qryL, 1024, 32);
        conv_img<true><<<dim3(32, 128), 256, 0, stream>>>(key, keyH, keyL, 1024, 32);

        // P = We @ Wq  -> PH/PL images
        gemm_img<3, 1><<<dim3(8, 8, 1), 256, 49152, stream>>>(
            WeH, WeL, WqTH, WqTL, nullptr, nullptr, PH, PL, 0, 0, 32, 0, 0, 32);
        // k = key @ Wk^T + bk -> kH/kL images
        gemm_img<3, 1><<<dim3(8, 128, 1), 256, 49152, stream>>>(
            keyH, keyL, WkH, WkL, nullptr, bk, kH, kL, 0, 0, 32, 0, 0, 32);
        // qw = query @ P^T + c -> qwH/qwL images (over dead key images)
        gemm_img<3, 1><<<dim3(8, 128, 1), 256, 49152, stream>>>(
            qryH, qryL, PH, PL, nullptr, cvec, qwH, qwL, 0, 0, 32, 0, 0, 32);
        // energy = qw @ k^T per batch -> attn region (seg-interleaved kernel)
        gemm_e3<<<dim3(16, 8, NB), 512, 0, stream>>>(
            qwH, qwL, kH, kL, attn,
            2048, (long long)S_LEN * S_LEN, 32, 16, 16);
        // value image (over dead kL), then v-proj -> vT image (over dead kH)
        conv_img<false><<<dim3(32, 128), 256, 0, stream>>>(value, valH, nullptr, 1024, 32);
        gemm_img<1, 3><<<dim3(8, 128, 1), 256, 49152, stream>>>(
            valH, nullptr, WvH, nullptr, nullptr, bv, vTH, nullptr, 0, 0, 32, 0, 0, 0);
        // softmax in place + attn bf16 image (over dead qry images)
        softmax_img<<<NB * S_LEN, 256, 0, stream>>>(attn, mask, attnH);
        // out = attn @ v per batch
        gemm_big<1><<<dim3(8, 8, NB), 512, 0, stream>>>(
            attnH, nullptr, vTH, nullptr, out, nullptr,
            1024, (long long)S_LEN * E_DIM, 64, 16, 8);
    } else {
        float* ws   = (float*)d_ws;
        float* WqT  = ws;
        float* P    = WqT + 1048576;
        float* cvec = P + 1048576;
        float* kbuf = cvec + 1024;
        float* qw   = kbuf + 16777216;
        float* vT   = qw + 16777216;
        const size_t need_old = (size_t)(1048576 * 2 + 1024 + 16777216 * 3) * 4;
        if (ws_size < need_old) return;

        transpose1024<<<dim3(32, 32), dim3(32, 8), 0, stream>>>(Wq, WqT);
        bias_c_kernel<<<1024, 256, 0, stream>>>(We, bq, cvec);
        gemm_split<true, 0><<<dim3(8, 8, 1), 256, 40960, stream>>>(
            We, WqT, P, nullptr, 1024, 1024, 1024, 0, 0, 0);
        gemm_split<true, 0><<<dim3(8, 128, 1), 256, 40960, stream>>>(
            key, Wk, kbuf, bk, 16384, 1024, 1024, 0, 0, 0);
        gemm_split<false, 1><<<dim3(8, 128, 1), 256, 20480, stream>>>(
            value, Wv, vT, bv, 16384, 1024, 1024, 0, 0, 0);
        gemm_split<true, 0><<<dim3(8, 128, 1), 256, 40960, stream>>>(
            query, P, qw, cvec, 16384, 1024, 1024, 0, 0, 0);
        gemm_split<true, 0><<<dim3(16, 16, NB), 256, 40960, stream>>>(
            qw, kbuf, attn, nullptr, 2048, 2048, 1024,
            (long long)S_LEN * E_DIM, (long long)S_LEN * E_DIM, (long long)S_LEN * S_LEN);
        softmax_rows<<<NB * S_LEN, 256, 0, stream>>>(attn, mask);
        gemm_split<false, 0><<<dim3(8, 16, NB), 256, 20480, stream>>>(
            attn, vT, out, nullptr, 2048, 1024, 2048,
            (long long)S_LEN * S_LEN, (long long)E_DIM * S_LEN, (long long)S_LEN * E_DIM);
    }

    (void)in_sizes; (void)n_in; (void)out_size;
}

// Round 10
// 793.752 us; speedup vs baseline: 4.7995x; 4.7995x over previous
//
#include <hip/hip_runtime.h>

// ---------------------------------------------------------------------------
// EBMAttention (B=8, S=2048, E=1024, H=1), fp32 in/out.
// Round 10: REVERT to the proven round-8 configuration (best: 791 us).
// Round 9's launch_bounds(512,6) spilled the f32x16 accumulators to scratch
// (VGPR 60->40, 14 GB spill traffic, MfmaUtil 3%).  Ring-3 72KB LDS +
// launch_bounds(512,4) restored for gemm_e3; gemm_big keeps the round-7
// single-barrier ring-3 shape.
// Math pipeline:
//   q_w = query @ P^T + c  (P = We@Wq),  k = key@Wk^T+bk,  v = value@Wv^T+bv
//   energy = q_w @ k^T; attn = softmax(-energy) (mask); out = attn @ v
// Pre-softmax GEMMs: 3-product hi/lo bf16 split (near-fp32 via MFMA).
// Operands are pre-tiled bf16 "LDS-images": per 128x32 tile, 16B chunk
// c = g*128 + r holds X[r][kt*32+g*8 .. +7].
// ---------------------------------------------------------------------------

typedef __attribute__((ext_vector_type(8))) short short8;
typedef __attribute__((ext_vector_type(4))) float f32x4;
typedef __attribute__((ext_vector_type(16))) float f32x16;

#define E_DIM 1024
#define S_LEN 2048
#define NB 8

// round-to-nearest-even fp32 -> bf16 bits
__device__ __forceinline__ unsigned short rne_bf(float x) {
    unsigned int u = __float_as_uint(x);
    return (unsigned short)((u + 0x7fffu + ((u >> 16) & 1u)) >> 16);
}

__device__ __forceinline__ void splitbf(float x, unsigned short& h, unsigned short& l) {
    unsigned int u = __float_as_uint(x);
    unsigned int rh = ((u + 0x7fffu + ((u >> 16) & 1u)) >> 16) << 16;
    h = (unsigned short)(rh >> 16);
    float r = x - __uint_as_float(rh);
    unsigned int v = __float_as_uint(r);
    l = (unsigned short)((v + 0x7fffu + ((v >> 16) & 1u)) >> 16);
}

__device__ __forceinline__ void lds_cp16(const void* g, void* l) {
    __builtin_amdgcn_global_load_lds(
        (const __attribute__((address_space(1))) unsigned int*)g,
        (__attribute__((address_space(3))) unsigned int*)l, 16, 0, 0);
}

__device__ __forceinline__ void wait_vm6() { asm volatile("s_waitcnt vmcnt(6)" ::: "memory"); }
__device__ __forceinline__ void wait_vm4() { asm volatile("s_waitcnt vmcnt(4)" ::: "memory"); }
__device__ __forceinline__ void wait_vm3() { asm volatile("s_waitcnt vmcnt(3)" ::: "memory"); }
__device__ __forceinline__ void wait_vm0() { asm volatile("s_waitcnt vmcnt(0)" ::: "memory"); }

// Bijective XCD-aware swizzle of (bx,by) within a z-plane.
__device__ __forceinline__ void swizzle_xy(int& bx, int& by) {
    const int gx = gridDim.x, gy = gridDim.y;
    const int nwg = gx * gy;
    const int w = by * gx + bx;
    if ((gx & 3) == 0 && (gy & 3) == 0 && (((gx >> 2) * (gy >> 2)) & 7) == 0) {
        const int nchx = gx >> 2;
        const int xcd = w & 7, i = w >> 3;
        const int j = i >> 4, p = i & 15;
        const int ch = xcd + 8 * j;
        const int chy = ch / nchx, chx = ch - chy * nchx;
        by = chy * 4 + (p >> 2);
        bx = chx * 4 + (p & 3);
    } else if ((nwg & 7) == 0) {
        const int cpx = nwg >> 3;
        const int sw = (w & 7) * cpx + (w >> 3);
        bx = sw % gx;
        by = sw / gx;
    }
}

// ---------------------------------------------------------------------------
// conv_img: fp32 [R x K] row-major -> h-image (+ l-image).  grid=(K/32, R/128)
// ---------------------------------------------------------------------------
template <bool DO_L>
__global__ __launch_bounds__(256) void conv_img(
    const float* __restrict__ src, unsigned short* __restrict__ h,
    unsigned short* __restrict__ l, int ld, int nkt)
{
    const int t = threadIdx.x;
    const long long tb = ((long long)blockIdx.y * nkt + blockIdx.x) * 4096;
    const float* s0 = src + (long long)blockIdx.y * 128 * ld + blockIdx.x * 32;
#pragma unroll
    for (int i = 0; i < 4; ++i) {
        const int f = i * 256 + t;
        const int r = f >> 3;
        const int c4 = (f & 7) << 2;
        const float4 v = *(const float4*)(s0 + (long long)r * ld + c4);
        const int gg = c4 >> 3;
        const int half = (c4 >> 2) & 1;
        const long long wo = tb + (long long)(gg * 128 + r) * 8 + half * 4;
        unsigned short h0, h1, h2, h3;
        if (DO_L) {
            unsigned short l0, l1, l2, l3;
            splitbf(v.x, h0, l0); splitbf(v.y, h1, l1);
            splitbf(v.z, h2, l2); splitbf(v.w, h3, l3);
            uint2 hp, lp;
            hp.x = h0 | ((unsigned)h1 << 16); hp.y = h2 | ((unsigned)h3 << 16);
            lp.x = l0 | ((unsigned)l1 << 16); lp.y = l2 | ((unsigned)l3 << 16);
            *(uint2*)(h + wo) = hp;
            *(uint2*)(l + wo) = lp;
        } else {
            h0 = rne_bf(v.x); h1 = rne_bf(v.y); h2 = rne_bf(v.z); h3 = rne_bf(v.w);
            uint2 hp;
            hp.x = h0 | ((unsigned)h1 << 16); hp.y = h2 | ((unsigned)h3 << 16);
            *(uint2*)(h + wo) = hp;
        }
    }
}

// ---------------------------------------------------------------------------
// conv_imgT: emit h+l images of src^T directly (src fp32 1024x1024).
// ---------------------------------------------------------------------------
__global__ __launch_bounds__(256) void conv_imgT(
    const float* __restrict__ src, unsigned short* __restrict__ h,
    unsigned short* __restrict__ l, int nkt)
{
    __shared__ float tile[32][132];
    const int t = threadIdx.x;
    const int kt = blockIdx.x;
    const int rb = blockIdx.y;
    const float* s0 = src + (long long)kt * 32 * E_DIM + rb * 128;
#pragma unroll
    for (int i = 0; i < 4; ++i) {
        const int f = i * 256 + t;
        const int r = f >> 5;
        const int c4 = (f & 31) << 2;
        const float4 v = *(const float4*)(s0 + (long long)r * E_DIM + c4);
        tile[r][c4] = v.x; tile[r][c4 + 1] = v.y;
        tile[r][c4 + 2] = v.z; tile[r][c4 + 3] = v.w;
    }
    __syncthreads();
    const long long tb = ((long long)rb * nkt + kt) * 4096;
#pragma unroll
    for (int i = 0; i < 2; ++i) {
        const int c = i * 256 + t;
        const int g = c >> 7, r = c & 127;
        unsigned short hh[8], ll[8];
#pragma unroll
        for (int j = 0; j < 8; ++j) splitbf(tile[g * 8 + j][r], hh[j], ll[j]);
        uint4 hp, lp;
        hp.x = hh[0] | ((unsigned)hh[1] << 16); hp.y = hh[2] | ((unsigned)hh[3] << 16);
        hp.z = hh[4] | ((unsigned)hh[5] << 16); hp.w = hh[6] | ((unsigned)hh[7] << 16);
        lp.x = ll[0] | ((unsigned)ll[1] << 16); lp.y = ll[2] | ((unsigned)ll[3] << 16);
        lp.z = ll[4] | ((unsigned)ll[5] << 16); lp.w = ll[6] | ((unsigned)ll[7] << 16);
        *(uint4*)(h + tb + (long long)c * 8) = hp;
        *(uint4*)(l + tb + (long long)c * 8) = lp;
    }
}

// ---------------------------------------------------------------------------
// gemm_e3: energy GEMM, seg-interleaved 3-product split.
// C[2048,2048] per z = A(qw) @ B(k)^T from h+l images, fp32 C out.
// 256x128 tile, BK=16, 8 waves (wave tile 64x64 = 2x2 of 32x32 MFMA).
// Per kt16: stage A-H(8K) A-L(8K) B-H+B-L(8K) into one 24KB buffer (ring-3),
// then clusters H*H, L*H, H*L (12 x mfma_f32_32x32x16_bf16) from same tiles.
// ---------------------------------------------------------------------------
__global__ __launch_bounds__(512, 4) void gemm_e3(
    const unsigned short* __restrict__ Ah, const unsigned short* __restrict__ Al,
    const unsigned short* __restrict__ Bh, const unsigned short* __restrict__ Bl,
    float* __restrict__ C, int ldC, long long bsC, int nkt32, int aZrb, int bZrb)
{
    __shared__ unsigned short smb[36864];   // 3 x 24KB

    const int t = threadIdx.x;
    const int wv = t >> 6, lane = t & 63;
    const int wr = wv >> 1, wc = wv & 1;
    const int l31 = lane & 31, lh = lane >> 5;

    int bx = blockIdx.x, by = blockIdx.y;
    swizzle_xy(bx, by);

    const long long aB0 = ((long long)blockIdx.z * aZrb + 2 * by) * nkt32 * 4096;
    const long long aB1 = aB0 + (long long)nkt32 * 4096;
    const long long bB0 = ((long long)blockIdx.z * bZrb + bx) * nkt32 * 4096;

    // stage kt16 step k16 into buffer c: A-H at [0,4096) shorts, A-L at
    // [4096,8192), B-H at [8192,10240), B-L at [10240,12288).
    const int rA = t & 255, glA = t >> 8;           // A chunk: row rA, k-half glA
    const int bc = t & 255;                          // B chunk within half
    auto stage = [&](int k16, int c) {
        unsigned short* buf = smb + c * 12288;
        const int kt32 = k16 >> 1, hh = k16 & 1;
        const long long aOff = ((rA >> 7) ? aB1 : aB0) + (long long)kt32 * 4096
                             + ((2 * hh + glA) * 128 + (rA & 127)) * 8;
        lds_cp16(Ah + aOff, buf + t * 8);
        lds_cp16(Al + aOff, buf + 4096 + t * 8);
        const long long bOff = bB0 + (long long)kt32 * 4096
                             + ((2 * hh + (bc >> 7)) * 128 + (bc & 127)) * 8;
        const unsigned short* bsrc = (t < 256) ? Bh : Bl;   // wave-uniform
        lds_cp16(bsrc + bOff, buf + 8192 + t * 8);
    };

    short8 ah[2], al[2], bh[2], bl[2];
    auto loadFrags = [&](int c) {
        const unsigned short* buf = smb + c * 12288;
#pragma unroll
        for (int m = 0; m < 2; ++m) {
            const int ra = lh * 256 + wr * 64 + m * 32 + l31;
            ah[m] = *(const short8*)(buf + ra * 8);
            al[m] = *(const short8*)(buf + 4096 + ra * 8);
        }
#pragma unroll
        for (int n = 0; n < 2; ++n) {
            const int rb = lh * 128 + wc * 64 + n * 32 + l31;
            bh[n] = *(const short8*)(buf + 8192 + rb * 8);
            bl[n] = *(const short8*)(buf + 10240 + rb * 8);
        }
    };

    f32x16 acc[2][2] = {};
    const int n16 = nkt32 * 2;

    stage(0, 0);
    stage(1, 1);

    for (int s = 0; s < n16; ++s) {
        __builtin_amdgcn_s_barrier();           // protect buf[(s+2)%3]
        if (s + 2 < n16) {
            stage(s + 2, (s + 2) % 3);
            wait_vm6();                          // own stage(s) landed
        } else if (s + 1 < n16) {
            wait_vm3();
        } else {
            wait_vm0();
        }
        __builtin_amdgcn_s_barrier();           // all waves' stage(s) landed
        __builtin_amdgcn_sched_barrier(0);
        loadFrags(s % 3);
        __builtin_amdgcn_s_setprio(1);
#pragma unroll
        for (int m = 0; m < 2; ++m)
#pragma unroll
            for (int n = 0; n < 2; ++n)
                acc[m][n] = __builtin_amdgcn_mfma_f32_32x32x16_bf16(ah[m], bh[n], acc[m][n], 0, 0, 0);
#pragma unroll
        for (int m = 0; m < 2; ++m)
#pragma unroll
            for (int n = 0; n < 2; ++n)
                acc[m][n] = __builtin_amdgcn_mfma_f32_32x32x16_bf16(al[m], bh[n], acc[m][n], 0, 0, 0);
#pragma unroll
        for (int m = 0; m < 2; ++m)
#pragma unroll
            for (int n = 0; n < 2; ++n)
                acc[m][n] = __builtin_amdgcn_mfma_f32_32x32x16_bf16(ah[m], bl[n], acc[m][n], 0, 0, 0);
        __builtin_amdgcn_s_setprio(0);
    }

    // 32x32 C/D layout: col = lane&31, row = (reg&3) + 8*(reg>>2) + 4*(lane>>5)
    float* Cb = C + (long long)blockIdx.z * bsC;
#pragma unroll
    for (int m = 0; m < 2; ++m)
#pragma unroll
        for (int n = 0; n < 2; ++n) {
            const int gc = bx * 128 + wc * 64 + n * 32 + l31;
            const int gr0 = by * 256 + wr * 64 + m * 32 + 4 * lh;
#pragma unroll
            for (int reg = 0; reg < 16; ++reg) {
                const int row = (reg & 3) + 8 * (reg >> 2);
                Cb[(long long)(gr0 + row) * ldC + gc] = acc[m][n][reg];
            }
        }
}

// ---------------------------------------------------------------------------
// gemm_big: 256x128 tile, 8 waves — used for the out-GEMM (NPROD=1).
// Round-7 single-barrier ring + register prefetch (unchanged).
// ---------------------------------------------------------------------------
template <int NPROD>
__global__ __launch_bounds__(512, 4) void gemm_big(
    const unsigned short* __restrict__ Ah, const unsigned short* __restrict__ Al,
    const unsigned short* __restrict__ Bh, const unsigned short* __restrict__ Bl,
    float* __restrict__ C, const float* __restrict__ bias,
    int ldC, long long bsC, int nkt, int aZrb, int bZrb)
{
    __shared__ unsigned short smb[36864];

    const int t = threadIdx.x;
    const int wv = t >> 6, lane = t & 63;
    const int wr = wv >> 1, wc = wv & 1;
    const int lr = lane & 15, gq = lane >> 4;

    int bx = blockIdx.x, by = blockIdx.y;
    swizzle_xy(bx, by);

    const long long aB0 = ((long long)blockIdx.z * aZrb + 2 * by) * nkt * 4096;
    const long long aB1 = aB0 + (long long)nkt * 4096;
    const long long bB0 = ((long long)blockIdx.z * bZrb + bx) * nkt * 4096;

    auto srcptr = [&](int s, const unsigned short*& a0, const unsigned short*& a1,
                      const unsigned short*& bS) {
        int seg, kt;
        if (NPROD == 3) {
            seg = (s >= 2 * nkt) ? 2 : (s >= nkt ? 1 : 0);
            kt = s - seg * nkt;
        } else { seg = 0; kt = s; }
        const unsigned short* aBase = ((NPROD == 3 && seg == 1) ? Al : Ah);
        const unsigned short* bBase = ((NPROD == 3 && seg == 2) ? Bl : Bh);
        a0 = aBase + aB0 + (long long)kt * 4096;
        a1 = aBase + aB1 + (long long)kt * 4096;
        bS = bBase + bB0 + (long long)kt * 4096;
    };
    auto stage = [&](const unsigned short* a0, const unsigned short* a1,
                     const unsigned short* bS, int c) {
        unsigned short* dA = smb + c * 12288;
        lds_cp16(a0 + t * 8, dA + t * 8);
        lds_cp16(a1 + t * 8, dA + 4096 + t * 8);
        lds_cp16(bS + t * 8, dA + 8192 + t * 8);
    };

    short8 af[4], bfr[4];
    auto loadFrags = [&](int c) {
        const unsigned short* dA = smb + c * 12288;
        const unsigned short* dB = dA + 8192;
#pragma unroll
        for (int m = 0; m < 4; ++m) {
            const int R = wr * 64 + m * 16 + lr;
            af[m] = *(const short8*)(dA + (R >> 7) * 4096 + (gq * 128 + (R & 127)) * 8);
        }
#pragma unroll
        for (int n = 0; n < 4; ++n) {
            const int Cc = wc * 64 + n * 16 + lr;
            bfr[n] = *(const short8*)(dB + (gq * 128 + Cc) * 8);
        }
    };

    f32x4 acc[4][4] = {};
    const int nsteps = NPROD * nkt;

    {
        const unsigned short *a0, *a1, *bS;
        srcptr(0, a0, a1, bS); stage(a0, a1, bS, 0);
        srcptr(1, a0, a1, bS); stage(a0, a1, bS, 1);
    }
    wait_vm3();
    __builtin_amdgcn_s_barrier();
    __builtin_amdgcn_sched_barrier(0);
    loadFrags(0);

    for (int s = 0; s < nsteps; ++s) {
        if (s + 2 < nsteps) {
            const unsigned short *a0, *a1, *bS;
            srcptr(s + 2, a0, a1, bS);
            stage(a0, a1, bS, (s + 2) % 3);
        }
        __builtin_amdgcn_sched_barrier(0);
        __builtin_amdgcn_s_setprio(1);
#pragma unroll
        for (int m = 0; m < 4; ++m)
#pragma unroll
            for (int n = 0; n < 4; ++n)
                acc[m][n] = __builtin_amdgcn_mfma_f32_16x16x32_bf16(af[m], bfr[n], acc[m][n], 0, 0, 0);
        __builtin_amdgcn_s_setprio(0);
        __builtin_amdgcn_sched_barrier(0);
        if (s + 1 < nsteps) {
            if (s + 2 < nsteps) wait_vm3();
            else wait_vm0();
            __builtin_amdgcn_s_barrier();
            __builtin_amdgcn_sched_barrier(0);
            loadFrags((s + 1) % 3);
        }
    }

    const int cr = (lane >> 4) << 2, cc = lane & 15;
    float* Cb = C + (long long)blockIdx.z * bsC;
#pragma unroll
    for (int m = 0; m < 4; ++m)
#pragma unroll
        for (int n = 0; n < 4; ++n) {
            const int gc = bx * 128 + wc * 64 + n * 16 + cc;
            const float badd = bias ? bias[gc] : 0.0f;
            const int gr0 = by * 256 + wr * 64 + m * 16 + cr;
#pragma unroll
            for (int i = 0; i < 4; ++i)
                Cb[(long long)(gr0 + i) * ldC + gc] = acc[m][n][i] + badd;
        }
}

// ---------------------------------------------------------------------------
// gemm_img: 128x128, 4 waves — image-emitting variants (WMODE 1 / 3).
// Round-7 structure (unchanged).  Dyn LDS 49152 B.
// ---------------------------------------------------------------------------
template <int NPROD, int WMODE>
__global__ __launch_bounds__(256) void gemm_img(
    const unsigned short* __restrict__ Ah, const unsigned short* __restrict__ Al,
    const unsigned short* __restrict__ Bh, const unsigned short* __restrict__ Bl,
    float* __restrict__ C, const float* __restrict__ bias,
    unsigned short* __restrict__ imgH, unsigned short* __restrict__ imgL,
    int ldC, long long bsC, int nkt, int aZrb, int bZrb, int outNkt)
{
    extern __shared__ unsigned short sm[];

    const int t = threadIdx.x;
    const int wv = t >> 6, lane = t & 63;
    const int wm = (wv >> 1) << 6, wn = (wv & 1) << 6;
    const int lr = lane & 15, gq = lane >> 4;

    int bx = blockIdx.x, by = blockIdx.y;
    swizzle_xy(bx, by);

    const long long aB0 = ((long long)blockIdx.z * aZrb + by) * nkt * 4096;
    const long long bB0 = ((long long)blockIdx.z * bZrb + bx) * nkt * 4096;

    auto srcptr = [&](int s, const unsigned short*& aS, const unsigned short*& bS) {
        int seg, kt;
        if (NPROD == 3) {
            seg = (s >= 2 * nkt) ? 2 : (s >= nkt ? 1 : 0);
            kt = s - seg * nkt;
        } else { seg = 0; kt = s; }
        aS = ((NPROD == 3 && seg == 1) ? Al : Ah) + aB0 + (long long)kt * 4096;
        bS = ((NPROD == 3 && seg == 2) ? Bl : Bh) + bB0 + (long long)kt * 4096;
    };
    auto stage = [&](const unsigned short* aS, const unsigned short* bS, int c) {
        unsigned short* dA = sm + c * 8192;
        unsigned short* dB = dA + 4096;
#pragma unroll
        for (int j = 0; j < 2; ++j) {
            lds_cp16(aS + (wv * 128 + j * 64 + lane) * 8, dA + (wv * 128 + j * 64) * 8);
            lds_cp16(bS + (wv * 128 + j * 64 + lane) * 8, dB + (wv * 128 + j * 64) * 8);
        }
    };

    short8 af[4], bfr[4];
    auto loadFrags = [&](int c) {
        const unsigned short* smA = sm + c * 8192;
        const unsigned short* smB = smA + 4096;
        const unsigned short* pa = smA + (gq * 128 + wm + lr) * 8;
        const unsigned short* pb = smB + (gq * 128 + wn + lr) * 8;
#pragma unroll
        for (int m = 0; m < 4; ++m) af[m] = *(const short8*)(pa + m * 128);
#pragma unroll
        for (int n = 0; n < 4; ++n) bfr[n] = *(const short8*)(pb + n * 128);
    };

    f32x4 acc[4][4] = {};
    const int nsteps = NPROD * nkt;

    {
        const unsigned short *aS, *bS;
        srcptr(0, aS, bS); stage(aS, bS, 0);
        srcptr(1, aS, bS); stage(aS, bS, 1);
    }
    wait_vm4();
    __builtin_amdgcn_s_barrier();
    __builtin_amdgcn_sched_barrier(0);
    loadFrags(0);

    for (int s = 0; s < nsteps; ++s) {
        if (s + 2 < nsteps) {
            const unsigned short *aS, *bS;
            srcptr(s + 2, aS, bS);
            stage(aS, bS, (s + 2) % 3);
        }
        __builtin_amdgcn_sched_barrier(0);
        __builtin_amdgcn_s_setprio(1);
#pragma unroll
        for (int m = 0; m < 4; ++m)
#pragma unroll
            for (int n = 0; n < 4; ++n)
                acc[m][n] = __builtin_amdgcn_mfma_f32_16x16x32_bf16(af[m], bfr[n], acc[m][n], 0, 0, 0);
        __builtin_amdgcn_s_setprio(0);
        __builtin_amdgcn_sched_barrier(0);
        if (s + 1 < nsteps) {
            if (s + 2 < nsteps) wait_vm4();
            else wait_vm0();
            __builtin_amdgcn_s_barrier();
            __builtin_amdgcn_sched_barrier(0);
            loadFrags((s + 1) % 3);
        }
    }

    const int cr = (lane >> 4) << 2, cc = lane & 15;
    if (WMODE == 0) {
        float* Cb = C + (long long)blockIdx.z * bsC;
#pragma unroll
        for (int m = 0; m < 4; ++m)
#pragma unroll
            for (int n = 0; n < 4; ++n) {
                const int gc = bx * 128 + wn + n * 16 + cc;
                const float badd = bias ? bias[gc] : 0.0f;
                const int gr0 = by * 128 + wm + m * 16 + cr;
#pragma unroll
                for (int i = 0; i < 4; ++i)
                    Cb[(long long)(gr0 + i) * ldC + gc] = acc[m][n][i] + badd;
            }
    } else {
        float* slab = (float*)sm;   // [2][16][132] fp32
        const int wmi = wv >> 1;
#pragma unroll
        for (int m = 0; m < 4; ++m) {
            __syncthreads();
#pragma unroll
            for (int n = 0; n < 4; ++n) {
                const int col = wn + n * 16 + cc;
                const float badd = bias ? bias[bx * 128 + col] : 0.0f;
#pragma unroll
                for (int i = 0; i < 4; ++i)
                    slab[(wmi * 16 + cr + i) * 132 + col] = acc[m][n][i] + badd;
            }
            __syncthreads();
            if (WMODE == 1) {
#pragma unroll
                for (int it = 0; it < 2; ++it) {
                    const int e = it * 256 + t;
                    const int wq = e >> 8, cg = (e >> 4) & 15, fr = e & 15;
                    const float* sp = slab + (wq * 16 + fr) * 132 + cg * 8;
                    const int rIn = wq * 64 + m * 16 + fr;
                    const int ktO = bx * 4 + (cg >> 2);
                    const int gO = cg & 3;
                    const long long base =
                        ((long long)by * outNkt + ktO) * 4096 + (gO * 128 + rIn) * 8;
                    unsigned short h[8], l[8];
#pragma unroll
                    for (int j = 0; j < 8; ++j) splitbf(sp[j], h[j], l[j]);
                    uint4 hp, lp;
                    hp.x = h[0] | ((unsigned)h[1] << 16); hp.y = h[2] | ((unsigned)h[3] << 16);
                    hp.z = h[4] | ((unsigned)h[5] << 16); hp.w = h[6] | ((unsigned)h[7] << 16);
                    lp.x = l[0] | ((unsigned)l[1] << 16); lp.y = l[2] | ((unsigned)l[3] << 16);
                    lp.z = l[4] | ((unsigned)l[5] << 16); lp.w = l[6] | ((unsigned)l[7] << 16);
                    *(uint4*)(imgH + base) = hp;
                    *(uint4*)(imgL + base) = lp;
                }
            } else {    // WMODE 3: vT image (B-layout over C^T), h only
#pragma unroll
                for (int it = 0; it < 2; ++it) {
                    const int e = it * 256 + t;
                    const int wq = e >> 8, s8 = (e >> 7) & 1, dl = e & 127;
                    const int sG = by * 128 + wq * 64 + m * 16 + s8 * 8;
                    const int z = sG >> 11, sIn = sG & 2047;
                    const int ktO = sIn >> 5, gO = (sIn >> 3) & 3;
                    const long long base =
                        ((long long)(z * 8 + bx) * 64 + ktO) * 4096 + (gO * 128 + dl) * 8;
                    unsigned short h[8];
#pragma unroll
                    for (int j = 0; j < 8; ++j)
                        h[j] = rne_bf(slab[(wq * 16 + s8 * 8 + j) * 132 + dl]);
                    uint4 hp;
                    hp.x = h[0] | ((unsigned)h[1] << 16); hp.y = h[2] | ((unsigned)h[3] << 16);
                    hp.z = h[4] | ((unsigned)h[5] << 16); hp.w = h[6] | ((unsigned)h[7] << 16);
                    *(uint4*)(imgH + base) = hp;
                }
            }
        }
    }
}

// ---------------------------------------------------------------------------
// softmax over rows of energy, in place; also emits bf16 A-image of attn.
// ---------------------------------------------------------------------------
__global__ __launch_bounds__(256) void softmax_img(
    float* __restrict__ attn, const int* __restrict__ mask,
    unsigned short* __restrict__ img)
{
    const int row = blockIdx.x;
    const int q = row & (S_LEN - 1);
    const int t = threadIdx.x;
    const int lane = t & 63, wid = t >> 6;
    float* rp = attn + (long long)row * S_LEN;
    const int* mp = mask + (long long)q * S_LEN;

    const float4 e0 = *(const float4*)(rp + t * 8);
    const float4 e1 = *(const float4*)(rp + t * 8 + 4);
    const int4 ma = *(const int4*)(mp + t * 8);
    const int4 mb = *(const int4*)(mp + t * 8 + 4);
    float zv[8];
    zv[0] = ma.x ? -e0.x : 1e9f;
    zv[1] = ma.y ? -e0.y : 1e9f;
    zv[2] = ma.z ? -e0.z : 1e9f;
    zv[3] = ma.w ? -e0.w : 1e9f;
    zv[4] = mb.x ? -e1.x : 1e9f;
    zv[5] = mb.y ? -e1.y : 1e9f;
    zv[6] = mb.z ? -e1.z : 1e9f;
    zv[7] = mb.w ? -e1.w : 1e9f;
    float mx = zv[0];
#pragma unroll
    for (int j = 1; j < 8; ++j) mx = fmaxf(mx, zv[j]);
#pragma unroll
    for (int o = 32; o > 0; o >>= 1) mx = fmaxf(mx, __shfl_xor(mx, o));
    __shared__ float redm[4], reds[4];
    if (lane == 0) redm[wid] = mx;
    __syncthreads();
    mx = fmaxf(fmaxf(redm[0], redm[1]), fmaxf(redm[2], redm[3]));
    float s = 0.f;
#pragma unroll
    for (int j = 0; j < 8; ++j) { zv[j] = expf(zv[j] - mx); s += zv[j]; }
#pragma unroll
    for (int o = 32; o > 0; o >>= 1) s += __shfl_xor(s, o);
    if (lane == 0) reds[wid] = s;
    __syncthreads();
    s = reds[0] + reds[1] + reds[2] + reds[3];
    const float inv = 1.0f / s;
    float4 o0, o1;
    o0.x = zv[0] * inv; o0.y = zv[1] * inv; o0.z = zv[2] * inv; o0.w = zv[3] * inv;
    o1.x = zv[4] * inv; o1.y = zv[5] * inv; o1.z = zv[6] * inv; o1.w = zv[7] * inv;
    *(float4*)(rp + t * 8) = o0;
    *(float4*)(rp + t * 8 + 4) = o1;
    const int z = row >> 11, rb = (row >> 7) & 15;
    const int ktO = t >> 2, gO = t & 3, r = row & 127;
    const long long base = (((long long)(z * 16 + rb) * 64 + ktO) * 512 + gO * 128 + r) * 8;
    uint4 hp;
    hp.x = rne_bf(o0.x) | ((unsigned)rne_bf(o0.y) << 16);
    hp.y = rne_bf(o0.z) | ((unsigned)rne_bf(o0.w) << 16);
    hp.z = rne_bf(o1.x) | ((unsigned)rne_bf(o1.y) << 16);
    hp.w = rne_bf(o1.z) | ((unsigned)rne_bf(o1.w) << 16);
    *(uint4*)(img + base) = hp;
}

// WqT[j][i] = Wq[i][j]  (1024x1024) — fallback path only
__global__ void transpose1024(const float* __restrict__ in, float* __restrict__ out)
{
    __shared__ float tile[32][33];
    const int bx = blockIdx.x << 5, by = blockIdx.y << 5;
    const int tx = threadIdx.x, ty = threadIdx.y;
#pragma unroll
    for (int i = 0; i < 4; ++i)
        tile[ty + 8 * i][tx] = in[(long long)(by + ty + 8 * i) * E_DIM + bx + tx];
    __syncthreads();
#pragma unroll
    for (int i = 0; i < 4; ++i)
        out[(long long)(bx + ty + 8 * i) * E_DIM + by + tx] = tile[tx][ty + 8 * i];
}

// c[i] = dot(bq, W_e[i,:])
__global__ __launch_bounds__(256) void bias_c_kernel(
    const float* __restrict__ We, const float* __restrict__ bq, float* __restrict__ c)
{
    const int i = blockIdx.x;
    const int t = threadIdx.x;
    float s = 0.f;
    for (int d = t; d < E_DIM; d += 256) s += bq[d] * We[(long long)i * E_DIM + d];
#pragma unroll
    for (int o = 32; o > 0; o >>= 1) s += __shfl_xor(s, o);
    __shared__ float red[4];
    if ((t & 63) == 0) red[t >> 6] = s;
    __syncthreads();
    if (t == 0) c[i] = red[0] + red[1] + red[2] + red[3];
}

// ---------------------------------------------------------------------------
// FALLBACK path (round-1 proven), used only if ws_size is too small.
// ---------------------------------------------------------------------------
template <bool SPLIT, int WMODE>
__global__ __launch_bounds__(256) void gemm_split(
    const float* __restrict__ A, const float* __restrict__ B,
    float* __restrict__ C, const float* __restrict__ bias,
    int M, int N, int K,
    long long bsA, long long bsB, long long bsC)
{
    extern __shared__ unsigned short sm[];
    unsigned short* sAh = sm;
    unsigned short* sBh = sm + 5120;
    unsigned short* sAl = sm + 10240;
    unsigned short* sBl = sm + 15360;

    const int t = threadIdx.x;
    const int z = blockIdx.z;
    const float* Ab = A + (long long)z * bsA + (long long)blockIdx.y * 128 * K;
    const float* Bb = B + (long long)z * bsB + (long long)blockIdx.x * 128 * K;

    const int wv = t >> 6;
    const int lane = t & 63;
    const int wm = (wv >> 1) << 6;
    const int wn = (wv & 1) << 6;
    const int lr = lane & 15;
    const int ko = (lane >> 4) << 3;

    f32x4 acc[4][4] = {};

    for (int k0 = 0; k0 < K; k0 += 32) {
        __syncthreads();
#pragma unroll
        for (int i = 0; i < 4; ++i) {
            const int f = t + (i << 8);
            const int row = f >> 3;
            const int c4 = (f & 7) << 2;
            const float4 av = *(const float4*)(Ab + (long long)row * K + k0 + c4);
            const float4 bv = *(const float4*)(Bb + (long long)row * K + k0 + c4);
            if (SPLIT) {
                unsigned short h0, h1, h2, h3, l0, l1, l2, l3;
                splitbf(av.x, h0, l0); splitbf(av.y, h1, l1);
                splitbf(av.z, h2, l2); splitbf(av.w, h3, l3);
                uint2 hp, lp;
                hp.x = (unsigned)h0 | ((unsigned)h1 << 16);
                hp.y = (unsigned)h2 | ((unsigned)h3 << 16);
                lp.x = (unsigned)l0 | ((unsigned)l1 << 16);
                lp.y = (unsigned)l2 | ((unsigned)l3 << 16);
                *(uint2*)(sAh + row * 40 + c4) = hp;
                *(uint2*)(sAl + row * 40 + c4) = lp;
                splitbf(bv.x, h0, l0); splitbf(bv.y, h1, l1);
                splitbf(bv.z, h2, l2); splitbf(bv.w, h3, l3);
                hp.x = (unsigned)h0 | ((unsigned)h1 << 16);
                hp.y = (unsigned)h2 | ((unsigned)h3 << 16);
                lp.x = (unsigned)l0 | ((unsigned)l1 << 16);
                lp.y = (unsigned)l2 | ((unsigned)l3 << 16);
                *(uint2*)(sBh + row * 40 + c4) = hp;
                *(uint2*)(sBl + row * 40 + c4) = lp;
            } else {
                uint2 hp;
                hp.x = (unsigned)rne_bf(av.x) | ((unsigned)rne_bf(av.y) << 16);
                hp.y = (unsigned)rne_bf(av.z) | ((unsigned)rne_bf(av.w) << 16);
                *(uint2*)(sAh + row * 40 + c4) = hp;
                hp.x = (unsigned)rne_bf(bv.x) | ((unsigned)rne_bf(bv.y) << 16);
                hp.y = (unsigned)rne_bf(bv.z) | ((unsigned)rne_bf(bv.w) << 16);
                *(uint2*)(sBh + row * 40 + c4) = hp;
            }
        }
        __syncthreads();
        short8 ah[4], bh[4], al[4], bl[4];
#pragma unroll
        for (int m = 0; m < 4; ++m)
            ah[m] = *(const short8*)(sAh + (wm + m * 16 + lr) * 40 + ko);
#pragma unroll
        for (int n = 0; n < 4; ++n)
            bh[n] = *(const short8*)(sBh + (wn + n * 16 + lr) * 40 + ko);
        if (SPLIT) {
#pragma unroll
            for (int m = 0; m < 4; ++m)
                al[m] = *(const short8*)(sAl + (wm + m * 16 + lr) * 40 + ko);
#pragma unroll
            for (int n = 0; n < 4; ++n)
                bl[n] = *(const short8*)(sBl + (wn + n * 16 + lr) * 40 + ko);
        }
#pragma unroll
        for (int m = 0; m < 4; ++m) {
#pragma unroll
            for (int n = 0; n < 4; ++n) {
                acc[m][n] = __builtin_amdgcn_mfma_f32_16x16x32_bf16(ah[m], bh[n], acc[m][n], 0, 0, 0);
                if (SPLIT) {
                    acc[m][n] = __builtin_amdgcn_mfma_f32_16x16x32_bf16(ah[m], bl[n], acc[m][n], 0, 0, 0);
                    acc[m][n] = __builtin_amdgcn_mfma_f32_16x16x32_bf16(al[m], bh[n], acc[m][n], 0, 0, 0);
                }
            }
        }
    }

    const int cr = (lane >> 4) << 2;
    const int cc = lane & 15;
    float* Cb = C + (long long)z * bsC;
#pragma unroll
    for (int m = 0; m < 4; ++m) {
#pragma unroll
        for (int n = 0; n < 4; ++n) {
            const int gc = blockIdx.x * 128 + wn + n * 16 + cc;
            const float badd = bias ? bias[gc] : 0.0f;
            const int gr0 = blockIdx.y * 128 + wm + m * 16 + cr;
#pragma unroll
            for (int i = 0; i < 4; ++i) {
                const float val = acc[m][n][i] + badd;
                if (WMODE == 0) {
                    Cb[(long long)(gr0 + i) * N + gc] = val;
                } else {
                    const int r = gr0 + i;
                    Cb[(long long)(r >> 11) * ((long long)N * 2048) +
                       (long long)gc * 2048 + (r & 2047)] = val;
                }
            }
        }
    }
}

__global__ __launch_bounds__(256) void softmax_rows(
    float* __restrict__ attn, const int* __restrict__ mask)
{
    const int row = blockIdx.x;
    const int q = row & (S_LEN - 1);
    const int t = threadIdx.x;
    const int lane = t & 63, wid = t >> 6;
    float* rp = attn + (long long)row * S_LEN;
    const int* mp = mask + (long long)q * S_LEN;

    float zv[8];
    float mx = -3.4e38f;
#pragma unroll
    for (int j = 0; j < 8; ++j) {
        const int idx = t + (j << 8);
        const float e = rp[idx];
        const int mv = mp[idx];
        const float zz = (mv != 0) ? -e : 1e9f;
        zv[j] = zz;
        mx = fmaxf(mx, zz);
    }
#pragma unroll
    for (int o = 32; o > 0; o >>= 1) mx = fmaxf(mx, __shfl_xor(mx, o));
    __shared__ float redm[4], reds[4];
    if (lane == 0) redm[wid] = mx;
    __syncthreads();
    mx = fmaxf(fmaxf(redm[0], redm[1]), fmaxf(redm[2], redm[3]));

    float s = 0.f;
#pragma unroll
    for (int j = 0; j < 8; ++j) { zv[j] = expf(zv[j] - mx); s += zv[j]; }
#pragma unroll
    for (int o = 32; o > 0; o >>= 1) s += __shfl_xor(s, o);
    if (lane == 0) reds[wid] = s;
    __syncthreads();
    s = reds[0] + reds[1] + reds[2] + reds[3];
    const float inv = 1.0f / s;
#pragma unroll
    for (int j = 0; j < 8; ++j) rp[t + (j << 8)] = zv[j] * inv;
}

// ---------------------------------------------------------------------------
extern "C" void kernel_launch(void* const* d_in, const int* in_sizes, int n_in,
                              void* d_out, int out_size, void* d_ws, size_t ws_size,
                              hipStream_t stream)
{
    const float* query = (const float*)d_in[0];
    const float* key   = (const float*)d_in[1];
    const float* value = (const float*)d_in[2];
    const int*   mask  = (const int*)d_in[3];
    const float* Wq    = (const float*)d_in[4];
    const float* bq    = (const float*)d_in[5];
    const float* Wk    = (const float*)d_in[6];
    const float* bk    = (const float*)d_in[7];
    const float* Wv    = (const float*)d_in[8];
    const float* bv    = (const float*)d_in[9];
    const float* We    = (const float*)d_in[10];

    float* out  = (float*)d_out;
    float* attn = out + (long long)NB * S_LEN * E_DIM;

    // ---------------- ws layout (byte offsets) ----------------
    const size_t oWqT  = 0;
    const size_t oCvec = oWqT + (4u << 20);
    const size_t oWqTH = oCvec + 4096;
    const size_t oWqTL = oWqTH + (2u << 20);
    const size_t oWeH  = oWqTL + (2u << 20);
    const size_t oWeL  = oWeH + (2u << 20);
    const size_t oWkH  = oWeL + (2u << 20);
    const size_t oWkL  = oWkH + (2u << 20);
    const size_t oWvH  = oWkL + (2u << 20);
    const size_t oPH   = oWvH + (2u << 20);
    const size_t oPL   = oPH + (2u << 20);
    const size_t oBig1 = oPL + (2u << 20);
    const size_t oBig2 = oBig1 + (64u << 20);
    const size_t oBig3 = oBig2 + (64u << 20);
    const size_t NEED  = oBig3 + (64u << 20);

    char* wsb = (char*)d_ws;

    if (ws_size >= NEED) {
        float* cvec = (float*)(wsb + oCvec);
        unsigned short* WqTH = (unsigned short*)(wsb + oWqTH);
        unsigned short* WqTL = (unsigned short*)(wsb + oWqTL);
        unsigned short* WeH  = (unsigned short*)(wsb + oWeH);
        unsigned short* WeL  = (unsigned short*)(wsb + oWeL);
        unsigned short* WkH  = (unsigned short*)(wsb + oWkH);
        unsigned short* WkL  = (unsigned short*)(wsb + oWkL);
        unsigned short* WvH  = (unsigned short*)(wsb + oWvH);
        unsigned short* PH   = (unsigned short*)(wsb + oPH);
        unsigned short* PL   = (unsigned short*)(wsb + oPL);
        unsigned short* qryH = (unsigned short*)(wsb + oBig1);
        unsigned short* qryL = (unsigned short*)(wsb + oBig1 + (32u << 20));
        unsigned short* attnH = (unsigned short*)(wsb + oBig1);           // alias
        unsigned short* keyH = (unsigned short*)(wsb + oBig2);
        unsigned short* keyL = (unsigned short*)(wsb + oBig2 + (32u << 20));
        unsigned short* qwH  = (unsigned short*)(wsb + oBig2);            // alias
        unsigned short* qwL  = (unsigned short*)(wsb + oBig2 + (32u << 20));
        unsigned short* kH   = (unsigned short*)(wsb + oBig3);
        unsigned short* kL   = (unsigned short*)(wsb + oBig3 + (32u << 20));
        unsigned short* vTH  = (unsigned short*)(wsb + oBig3);            // alias
        unsigned short* valH = (unsigned short*)(wsb + oBig3 + (32u << 20));

        bias_c_kernel<<<1024, 256, 0, stream>>>(We, bq, cvec);
        conv_imgT<<<dim3(32, 8), 256, 0, stream>>>(Wq, WqTH, WqTL, 32);
        conv_img<true><<<dim3(32, 8), 256, 0, stream>>>(We, WeH, WeL, 1024, 32);
        conv_img<true><<<dim3(32, 8), 256, 0, stream>>>(Wk, WkH, WkL, 1024, 32);
        conv_img<false><<<dim3(32, 8), 256, 0, stream>>>(Wv, WvH, nullptr, 1024, 32);
        conv_img<true><<<dim3(32, 128), 256, 0, stream>>>(query, qryH, qryL, 1024, 32);
        conv_img<true><<<dim3(32, 128), 256, 0, stream>>>(key, keyH, keyL, 1024, 32);

        // P = We @ Wq  -> PH/PL images
        gemm_img<3, 1><<<dim3(8, 8, 1), 256, 49152, stream>>>(
            WeH, WeL, WqTH, WqTL, nullptr, nullptr, PH, PL, 0, 0, 32, 0, 0, 32);
        // k = key @ Wk^T + bk -> kH/kL images
        gemm_img<3, 1><<<dim3(8, 128, 1), 256, 49152, stream>>>(
            keyH, keyL, WkH, WkL, nullptr, bk, kH, kL, 0, 0, 32, 0, 0, 32);
        // qw = query @ P^T + c -> qwH/qwL images (over dead key images)
        gemm_img<3, 1><<<dim3(8, 128, 1), 256, 49152, stream>>>(
            qryH, qryL, PH, PL, nullptr, cvec, qwH, qwL, 0, 0, 32, 0, 0, 32);
        // energy = qw @ k^T per batch -> attn region (seg-interleaved kernel)
        gemm_e3<<<dim3(16, 8, NB), 512, 0, stream>>>(
            qwH, qwL, kH, kL, attn,
            2048, (long long)S_LEN * S_LEN, 32, 16, 16);
        // value image (over dead kL), then v-proj -> vT image (over dead kH)
        conv_img<false><<<dim3(32, 128), 256, 0, stream>>>(value, valH, nullptr, 1024, 32);
        gemm_img<1, 3><<<dim3(8, 128, 1), 256, 49152, stream>>>(
            valH, nullptr, WvH, nullptr, nullptr, bv, vTH, nullptr, 0, 0, 32, 0, 0, 0);
        // softmax in place + attn bf16 image (over dead qry images)
        softmax_img<<<NB * S_LEN, 256, 0, stream>>>(attn, mask, attnH);
        // out = attn @ v per batch
        gemm_big<1><<<dim3(8, 8, NB), 512, 0, stream>>>(
            attnH, nullptr, vTH, nullptr, out, nullptr,
            1024, (long long)S_LEN * E_DIM, 64, 16, 8);
    } else {
        float* ws   = (float*)d_ws;
        float* WqT  = ws;
        float* P    = WqT + 1048576;
        float* cvec = P + 1048576;
        float* kbuf = cvec + 1024;
        float* qw   = kbuf + 16777216;
        float* vT   = qw + 16777216;
        const size_t need_old = (size_t)(1048576 * 2 + 1024 + 16777216 * 3) * 4;
        if (ws_size < need_old) return;

        transpose1024<<<dim3(32, 32), dim3(32, 8), 0, stream>>>(Wq, WqT);
        bias_c_kernel<<<1024, 256, 0, stream>>>(We, bq, cvec);
        gemm_split<true, 0><<<dim3(8, 8, 1), 256, 40960, stream>>>(
            We, WqT, P, nullptr, 1024, 1024, 1024, 0, 0, 0);
        gemm_split<true, 0><<<dim3(8, 128, 1), 256, 40960, stream>>>(
            key, Wk, kbuf, bk, 16384, 1024, 1024, 0, 0, 0);
        gemm_split<false, 1><<<dim3(8, 128, 1), 256, 20480, stream>>>(
            value, Wv, vT, bv, 16384, 1024, 1024, 0, 0, 0);
        gemm_split<true, 0><<<dim3(8, 128, 1), 256, 40960, stream>>>(
            query, P, qw, cvec, 16384, 1024, 1024, 0, 0, 0);
        gemm_split<true, 0><<<dim3(16, 16, NB), 256, 40960, stream>>>(
            qw, kbuf, attn, nullptr, 2048, 2048, 1024,
            (long long)S_LEN * E_DIM, (long long)S_LEN * E_DIM, (long long)S_LEN * S_LEN);
        softmax_rows<<<NB * S_LEN, 256, 0, stream>>>(attn, mask);
        gemm_split<false, 0><<<dim3(8, 16, NB), 256, 20480, stream>>>(
            attn, vT, out, nullptr, 2048, 1024, 2048,
            (long long)S_LEN * S_LEN, (long long)E_DIM * S_LEN, (long long)S_LEN * E_DIM);
    }

    (void)in_sizes; (void)n_in; (void)out_size;
}

// Round 11
// 768.461 us; speedup vs baseline: 4.9574x; 1.0329x over previous
//
#include <hip/hip_runtime.h>

// ---------------------------------------------------------------------------
// EBMAttention (B=8, S=2048, E=1024, H=1), fp32 in/out.
// Round 11: weight-folding. energy = query.G.key^T with G = Wq^T We^T Wk:
//   PT = Wq^T.We^T (tiny), GT = Wk^T.(PT)^T = G^T (tiny), qg = query.G (big),
//   energy = qg.key^T (+ r[col]).  This deletes one 16384x1024x1024 3-product
//   projection (the old k-proj).  Bias generality: row-constant bias terms
//   vanish under row-softmax; only r = key.(Wk^T.We.bq) survives (column
//   bias added in gemm_e3 epilogue; zero for this workload).
// Pre-softmax GEMMs: 3-product hi/lo bf16 split (near-fp32 via MFMA).
// Operands are pre-tiled bf16 "LDS-images": per 128x32 tile, 16B chunk
// c = g*128 + r holds X[r][kt*32+g*8 .. +7].
// ---------------------------------------------------------------------------

typedef __attribute__((ext_vector_type(8))) short short8;
typedef __attribute__((ext_vector_type(4))) float f32x4;
typedef __attribute__((ext_vector_type(16))) float f32x16;

#define E_DIM 1024
#define S_LEN 2048
#define NB 8

// round-to-nearest-even fp32 -> bf16 bits
__device__ __forceinline__ unsigned short rne_bf(float x) {
    unsigned int u = __float_as_uint(x);
    return (unsigned short)((u + 0x7fffu + ((u >> 16) & 1u)) >> 16);
}

__device__ __forceinline__ void splitbf(float x, unsigned short& h, unsigned short& l) {
    unsigned int u = __float_as_uint(x);
    unsigned int rh = ((u + 0x7fffu + ((u >> 16) & 1u)) >> 16) << 16;
    h = (unsigned short)(rh >> 16);
    float r = x - __uint_as_float(rh);
    unsigned int v = __float_as_uint(r);
    l = (unsigned short)((v + 0x7fffu + ((v >> 16) & 1u)) >> 16);
}

__device__ __forceinline__ void lds_cp16(const void* g, void* l) {
    __builtin_amdgcn_global_load_lds(
        (const __attribute__((address_space(1))) unsigned int*)g,
        (__attribute__((address_space(3))) unsigned int*)l, 16, 0, 0);
}

__device__ __forceinline__ void wait_vm6() { asm volatile("s_waitcnt vmcnt(6)" ::: "memory"); }
__device__ __forceinline__ void wait_vm4() { asm volatile("s_waitcnt vmcnt(4)" ::: "memory"); }
__device__ __forceinline__ void wait_vm3() { asm volatile("s_waitcnt vmcnt(3)" ::: "memory"); }
__device__ __forceinline__ void wait_vm0() { asm volatile("s_waitcnt vmcnt(0)" ::: "memory"); }

// Bijective XCD-aware swizzle of (bx,by) within a z-plane.
__device__ __forceinline__ void swizzle_xy(int& bx, int& by) {
    const int gx = gridDim.x, gy = gridDim.y;
    const int nwg = gx * gy;
    const int w = by * gx + bx;
    if ((gx & 3) == 0 && (gy & 3) == 0 && (((gx >> 2) * (gy >> 2)) & 7) == 0) {
        const int nchx = gx >> 2;
        const int xcd = w & 7, i = w >> 3;
        const int j = i >> 4, p = i & 15;
        const int ch = xcd + 8 * j;
        const int chy = ch / nchx, chx = ch - chy * nchx;
        by = chy * 4 + (p >> 2);
        bx = chx * 4 + (p & 3);
    } else if ((nwg & 7) == 0) {
        const int cpx = nwg >> 3;
        const int sw = (w & 7) * cpx + (w >> 3);
        bx = sw % gx;
        by = sw / gx;
    }
}

// ---------------------------------------------------------------------------
// conv_img: fp32 [R x K] row-major -> h-image (+ l-image).  grid=(K/32, R/128)
// ---------------------------------------------------------------------------
template <bool DO_L>
__global__ __launch_bounds__(256) void conv_img(
    const float* __restrict__ src, unsigned short* __restrict__ h,
    unsigned short* __restrict__ l, int ld, int nkt)
{
    const int t = threadIdx.x;
    const long long tb = ((long long)blockIdx.y * nkt + blockIdx.x) * 4096;
    const float* s0 = src + (long long)blockIdx.y * 128 * ld + blockIdx.x * 32;
#pragma unroll
    for (int i = 0; i < 4; ++i) {
        const int f = i * 256 + t;
        const int r = f >> 3;
        const int c4 = (f & 7) << 2;
        const float4 v = *(const float4*)(s0 + (long long)r * ld + c4);
        const int gg = c4 >> 3;
        const int half = (c4 >> 2) & 1;
        const long long wo = tb + (long long)(gg * 128 + r) * 8 + half * 4;
        unsigned short h0, h1, h2, h3;
        if (DO_L) {
            unsigned short l0, l1, l2, l3;
            splitbf(v.x, h0, l0); splitbf(v.y, h1, l1);
            splitbf(v.z, h2, l2); splitbf(v.w, h3, l3);
            uint2 hp, lp;
            hp.x = h0 | ((unsigned)h1 << 16); hp.y = h2 | ((unsigned)h3 << 16);
            lp.x = l0 | ((unsigned)l1 << 16); lp.y = l2 | ((unsigned)l3 << 16);
            *(uint2*)(h + wo) = hp;
            *(uint2*)(l + wo) = lp;
        } else {
            h0 = rne_bf(v.x); h1 = rne_bf(v.y); h2 = rne_bf(v.z); h3 = rne_bf(v.w);
            uint2 hp;
            hp.x = h0 | ((unsigned)h1 << 16); hp.y = h2 | ((unsigned)h3 << 16);
            *(uint2*)(h + wo) = hp;
        }
    }
}

// ---------------------------------------------------------------------------
// conv_imgT: emit h+l images of src^T directly (src fp32 1024x1024).
// ---------------------------------------------------------------------------
__global__ __launch_bounds__(256) void conv_imgT(
    const float* __restrict__ src, unsigned short* __restrict__ h,
    unsigned short* __restrict__ l, int nkt)
{
    __shared__ float tile[32][132];
    const int t = threadIdx.x;
    const int kt = blockIdx.x;
    const int rb = blockIdx.y;
    const float* s0 = src + (long long)kt * 32 * E_DIM + rb * 128;
#pragma unroll
    for (int i = 0; i < 4; ++i) {
        const int f = i * 256 + t;
        const int r = f >> 5;
        const int c4 = (f & 31) << 2;
        const float4 v = *(const float4*)(s0 + (long long)r * E_DIM + c4);
        tile[r][c4] = v.x; tile[r][c4 + 1] = v.y;
        tile[r][c4 + 2] = v.z; tile[r][c4 + 3] = v.w;
    }
    __syncthreads();
    const long long tb = ((long long)rb * nkt + kt) * 4096;
#pragma unroll
    for (int i = 0; i < 2; ++i) {
        const int c = i * 256 + t;
        const int g = c >> 7, r = c & 127;
        unsigned short hh[8], ll[8];
#pragma unroll
        for (int j = 0; j < 8; ++j) splitbf(tile[g * 8 + j][r], hh[j], ll[j]);
        uint4 hp, lp;
        hp.x = hh[0] | ((unsigned)hh[1] << 16); hp.y = hh[2] | ((unsigned)hh[3] << 16);
        hp.z = hh[4] | ((unsigned)hh[5] << 16); hp.w = hh[6] | ((unsigned)hh[7] << 16);
        lp.x = ll[0] | ((unsigned)ll[1] << 16); lp.y = ll[2] | ((unsigned)ll[3] << 16);
        lp.z = ll[4] | ((unsigned)ll[5] << 16); lp.w = ll[6] | ((unsigned)ll[7] << 16);
        *(uint4*)(h + tb + (long long)c * 8) = hp;
        *(uint4*)(l + tb + (long long)c * 8) = lp;
    }
}

// w[i] = sum_d Wk[d][i] * t1[d]   (Wk^T . t1), grid 4 x 256
__global__ __launch_bounds__(256) void wvecT_kernel(
    const float* __restrict__ Wk, const float* __restrict__ t1, float* __restrict__ w)
{
    const int i = blockIdx.x * 256 + threadIdx.x;
    float s = 0.f;
    for (int d = 0; d < E_DIM; ++d) s += Wk[(long long)d * E_DIM + i] * t1[d];
    w[i] = s;
}

// r[row] = key[row,:] . w   over B*S rows
__global__ __launch_bounds__(256) void rvec_kernel(
    const float* __restrict__ key, const float* __restrict__ w, float* __restrict__ r)
{
    const int row = blockIdx.x;
    const int t = threadIdx.x;
    const float4 kv = ((const float4*)(key + (long long)row * E_DIM))[t];
    const float4 wv = ((const float4*)w)[t];
    float s = kv.x * wv.x + kv.y * wv.y + kv.z * wv.z + kv.w * wv.w;
#pragma unroll
    for (int o = 32; o > 0; o >>= 1) s += __shfl_xor(s, o);
    __shared__ float red[4];
    if ((t & 63) == 0) red[t >> 6] = s;
    __syncthreads();
    if (t == 0) r[row] = red[0] + red[1] + red[2] + red[3];
}

// ---------------------------------------------------------------------------
// gemm_e3: energy GEMM, seg-interleaved 3-product split + column bias r.
// C[2048,2048] per z = A(qg) @ B(key)^T + r[z*2048+col], fp32 out.
// 256x128 tile, BK=16, 8 waves (wave tile 64x64 = 2x2 of 32x32 MFMA).
// Ring-3 x 24KB (72KB LDS), launch_bounds(512,4)  [DO NOT raise: rnd-9 spill]
// ---------------------------------------------------------------------------
__global__ __launch_bounds__(512, 4) void gemm_e3(
    const unsigned short* __restrict__ Ah, const unsigned short* __restrict__ Al,
    const unsigned short* __restrict__ Bh, const unsigned short* __restrict__ Bl,
    const float* __restrict__ rbias,
    float* __restrict__ C, int ldC, long long bsC, int nkt32, int aZrb, int bZrb)
{
    __shared__ unsigned short smb[36864];   // 3 x 24KB

    const int t = threadIdx.x;
    const int wv = t >> 6, lane = t & 63;
    const int wr = wv >> 1, wc = wv & 1;
    const int l31 = lane & 31, lh = lane >> 5;

    int bx = blockIdx.x, by = blockIdx.y;
    swizzle_xy(bx, by);

    const long long aB0 = ((long long)blockIdx.z * aZrb + 2 * by) * nkt32 * 4096;
    const long long aB1 = aB0 + (long long)nkt32 * 4096;
    const long long bB0 = ((long long)blockIdx.z * bZrb + bx) * nkt32 * 4096;

    const int rA = t & 255, glA = t >> 8;
    const int bc = t & 255;
    auto stage = [&](int k16, int c) {
        unsigned short* buf = smb + c * 12288;
        const int kt32 = k16 >> 1, hh = k16 & 1;
        const long long aOff = ((rA >> 7) ? aB1 : aB0) + (long long)kt32 * 4096
                             + ((2 * hh + glA) * 128 + (rA & 127)) * 8;
        lds_cp16(Ah + aOff, buf + t * 8);
        lds_cp16(Al + aOff, buf + 4096 + t * 8);
        const long long bOff = bB0 + (long long)kt32 * 4096
                             + ((2 * hh + (bc >> 7)) * 128 + (bc & 127)) * 8;
        const unsigned short* bsrc = (t < 256) ? Bh : Bl;   // wave-uniform
        lds_cp16(bsrc + bOff, buf + 8192 + t * 8);
    };

    short8 ah[2], al[2], bh[2], bl[2];
    auto loadFrags = [&](int c) {
        const unsigned short* buf = smb + c * 12288;
#pragma unroll
        for (int m = 0; m < 2; ++m) {
            const int ra = lh * 256 + wr * 64 + m * 32 + l31;
            ah[m] = *(const short8*)(buf + ra * 8);
            al[m] = *(const short8*)(buf + 4096 + ra * 8);
        }
#pragma unroll
        for (int n = 0; n < 2; ++n) {
            const int rb = lh * 128 + wc * 64 + n * 32 + l31;
            bh[n] = *(const short8*)(buf + 8192 + rb * 8);
            bl[n] = *(const short8*)(buf + 10240 + rb * 8);
        }
    };

    f32x16 acc[2][2] = {};
    const int n16 = nkt32 * 2;

    stage(0, 0);
    stage(1, 1);

    for (int s = 0; s < n16; ++s) {
        __builtin_amdgcn_s_barrier();           // protect buf[(s+2)%3]
        if (s + 2 < n16) {
            stage(s + 2, (s + 2) % 3);
            wait_vm6();                          // own stage(s) landed
        } else if (s + 1 < n16) {
            wait_vm3();
        } else {
            wait_vm0();
        }
        __builtin_amdgcn_s_barrier();           // all waves' stage(s) landed
        __builtin_amdgcn_sched_barrier(0);
        loadFrags(s % 3);
        __builtin_amdgcn_s_setprio(1);
#pragma unroll
        for (int m = 0; m < 2; ++m)
#pragma unroll
            for (int n = 0; n < 2; ++n)
                acc[m][n] = __builtin_amdgcn_mfma_f32_32x32x16_bf16(ah[m], bh[n], acc[m][n], 0, 0, 0);
#pragma unroll
        for (int m = 0; m < 2; ++m)
#pragma unroll
            for (int n = 0; n < 2; ++n)
                acc[m][n] = __builtin_amdgcn_mfma_f32_32x32x16_bf16(al[m], bh[n], acc[m][n], 0, 0, 0);
#pragma unroll
        for (int m = 0; m < 2; ++m)
#pragma unroll
            for (int n = 0; n < 2; ++n)
                acc[m][n] = __builtin_amdgcn_mfma_f32_32x32x16_bf16(ah[m], bl[n], acc[m][n], 0, 0, 0);
        __builtin_amdgcn_s_setprio(0);
    }

    // 32x32 C/D layout: col = lane&31, row = (reg&3) + 8*(reg>>2) + 4*(lane>>5)
    float* Cb = C + (long long)blockIdx.z * bsC;
#pragma unroll
    for (int m = 0; m < 2; ++m)
#pragma unroll
        for (int n = 0; n < 2; ++n) {
            const int gc = bx * 128 + wc * 64 + n * 32 + l31;
            const float rb = rbias ? rbias[(long long)blockIdx.z * 2048 + gc] : 0.0f;
            const int gr0 = by * 256 + wr * 64 + m * 32 + 4 * lh;
#pragma unroll
            for (int reg = 0; reg < 16; ++reg) {
                const int row = (reg & 3) + 8 * (reg >> 2);
                Cb[(long long)(gr0 + row) * ldC + gc] = acc[m][n][reg] + rb;
            }
        }
}

// ---------------------------------------------------------------------------
// gemm_big: 256x128 tile, 8 waves — used for the out-GEMM (NPROD=1).
// Round-7 single-barrier ring + register prefetch (unchanged).
// ---------------------------------------------------------------------------
template <int NPROD>
__global__ __launch_bounds__(512, 4) void gemm_big(
    const unsigned short* __restrict__ Ah, const unsigned short* __restrict__ Al,
    const unsigned short* __restrict__ Bh, const unsigned short* __restrict__ Bl,
    float* __restrict__ C, const float* __restrict__ bias,
    int ldC, long long bsC, int nkt, int aZrb, int bZrb)
{
    __shared__ unsigned short smb[36864];

    const int t = threadIdx.x;
    const int wv = t >> 6, lane = t & 63;
    const int wr = wv >> 1, wc = wv & 1;
    const int lr = lane & 15, gq = lane >> 4;

    int bx = blockIdx.x, by = blockIdx.y;
    swizzle_xy(bx, by);

    const long long aB0 = ((long long)blockIdx.z * aZrb + 2 * by) * nkt * 4096;
    const long long aB1 = aB0 + (long long)nkt * 4096;
    const long long bB0 = ((long long)blockIdx.z * bZrb + bx) * nkt * 4096;

    auto srcptr = [&](int s, const unsigned short*& a0, const unsigned short*& a1,
                      const unsigned short*& bS) {
        int seg, kt;
        if (NPROD == 3) {
            seg = (s >= 2 * nkt) ? 2 : (s >= nkt ? 1 : 0);
            kt = s - seg * nkt;
        } else { seg = 0; kt = s; }
        const unsigned short* aBase = ((NPROD == 3 && seg == 1) ? Al : Ah);
        const unsigned short* bBase = ((NPROD == 3 && seg == 2) ? Bl : Bh);
        a0 = aBase + aB0 + (long long)kt * 4096;
        a1 = aBase + aB1 + (long long)kt * 4096;
        bS = bBase + bB0 + (long long)kt * 4096;
    };
    auto stage = [&](const unsigned short* a0, const unsigned short* a1,
                     const unsigned short* bS, int c) {
        unsigned short* dA = smb + c * 12288;
        lds_cp16(a0 + t * 8, dA + t * 8);
        lds_cp16(a1 + t * 8, dA + 4096 + t * 8);
        lds_cp16(bS + t * 8, dA + 8192 + t * 8);
    };

    short8 af[4], bfr[4];
    auto loadFrags = [&](int c) {
        const unsigned short* dA = smb + c * 12288;
        const unsigned short* dB = dA + 8192;
#pragma unroll
        for (int m = 0; m < 4; ++m) {
            const int R = wr * 64 + m * 16 + lr;
            af[m] = *(const short8*)(dA + (R >> 7) * 4096 + (gq * 128 + (R & 127)) * 8);
        }
#pragma unroll
        for (int n = 0; n < 4; ++n) {
            const int Cc = wc * 64 + n * 16 + lr;
            bfr[n] = *(const short8*)(dB + (gq * 128 + Cc) * 8);
        }
    };

    f32x4 acc[4][4] = {};
    const int nsteps = NPROD * nkt;

    {
        const unsigned short *a0, *a1, *bS;
        srcptr(0, a0, a1, bS); stage(a0, a1, bS, 0);
        srcptr(1, a0, a1, bS); stage(a0, a1, bS, 1);
    }
    wait_vm3();
    __builtin_amdgcn_s_barrier();
    __builtin_amdgcn_sched_barrier(0);
    loadFrags(0);

    for (int s = 0; s < nsteps; ++s) {
        if (s + 2 < nsteps) {
            const unsigned short *a0, *a1, *bS;
            srcptr(s + 2, a0, a1, bS);
            stage(a0, a1, bS, (s + 2) % 3);
        }
        __builtin_amdgcn_sched_barrier(0);
        __builtin_amdgcn_s_setprio(1);
#pragma unroll
        for (int m = 0; m < 4; ++m)
#pragma unroll
            for (int n = 0; n < 4; ++n)
                acc[m][n] = __builtin_amdgcn_mfma_f32_16x16x32_bf16(af[m], bfr[n], acc[m][n], 0, 0, 0);
        __builtin_amdgcn_s_setprio(0);
        __builtin_amdgcn_sched_barrier(0);
        if (s + 1 < nsteps) {
            if (s + 2 < nsteps) wait_vm3();
            else wait_vm0();
            __builtin_amdgcn_s_barrier();
            __builtin_amdgcn_sched_barrier(0);
            loadFrags((s + 1) % 3);
        }
    }

    const int cr = (lane >> 4) << 2, cc = lane & 15;
    float* Cb = C + (long long)blockIdx.z * bsC;
#pragma unroll
    for (int m = 0; m < 4; ++m)
#pragma unroll
        for (int n = 0; n < 4; ++n) {
            const int gc = bx * 128 + wc * 64 + n * 16 + cc;
            const float badd = bias ? bias[gc] : 0.0f;
            const int gr0 = by * 256 + wr * 64 + m * 16 + cr;
#pragma unroll
            for (int i = 0; i < 4; ++i)
                Cb[(long long)(gr0 + i) * ldC + gc] = acc[m][n][i] + badd;
        }
}

// ---------------------------------------------------------------------------
// gemm_img: 128x128, 4 waves — image-emitting variants (WMODE 1 / 3).
// Round-7 structure (unchanged).  Dyn LDS 49152 B.
// ---------------------------------------------------------------------------
template <int NPROD, int WMODE>
__global__ __launch_bounds__(256) void gemm_img(
    const unsigned short* __restrict__ Ah, const unsigned short* __restrict__ Al,
    const unsigned short* __restrict__ Bh, const unsigned short* __restrict__ Bl,
    float* __restrict__ C, const float* __restrict__ bias,
    unsigned short* __restrict__ imgH, unsigned short* __restrict__ imgL,
    int ldC, long long bsC, int nkt, int aZrb, int bZrb, int outNkt)
{
    extern __shared__ unsigned short sm[];

    const int t = threadIdx.x;
    const int wv = t >> 6, lane = t & 63;
    const int wm = (wv >> 1) << 6, wn = (wv & 1) << 6;
    const int lr = lane & 15, gq = lane >> 4;

    int bx = blockIdx.x, by = blockIdx.y;
    swizzle_xy(bx, by);

    const long long aB0 = ((long long)blockIdx.z * aZrb + by) * nkt * 4096;
    const long long bB0 = ((long long)blockIdx.z * bZrb + bx) * nkt * 4096;

    auto srcptr = [&](int s, const unsigned short*& aS, const unsigned short*& bS) {
        int seg, kt;
        if (NPROD == 3) {
            seg = (s >= 2 * nkt) ? 2 : (s >= nkt ? 1 : 0);
            kt = s - seg * nkt;
        } else { seg = 0; kt = s; }
        aS = ((NPROD == 3 && seg == 1) ? Al : Ah) + aB0 + (long long)kt * 4096;
        bS = ((NPROD == 3 && seg == 2) ? Bl : Bh) + bB0 + (long long)kt * 4096;
    };
    auto stage = [&](const unsigned short* aS, const unsigned short* bS, int c) {
        unsigned short* dA = sm + c * 8192;
        unsigned short* dB = dA + 4096;
#pragma unroll
        for (int j = 0; j < 2; ++j) {
            lds_cp16(aS + (wv * 128 + j * 64 + lane) * 8, dA + (wv * 128 + j * 64) * 8);
            lds_cp16(bS + (wv * 128 + j * 64 + lane) * 8, dB + (wv * 128 + j * 64) * 8);
        }
    };

    short8 af[4], bfr[4];
    auto loadFrags = [&](int c) {
        const unsigned short* smA = sm + c * 8192;
        const unsigned short* smB = smA + 4096;
        const unsigned short* pa = smA + (gq * 128 + wm + lr) * 8;
        const unsigned short* pb = smB + (gq * 128 + wn + lr) * 8;
#pragma unroll
        for (int m = 0; m < 4; ++m) af[m] = *(const short8*)(pa + m * 128);
#pragma unroll
        for (int n = 0; n < 4; ++n) bfr[n] = *(const short8*)(pb + n * 128);
    };

    f32x4 acc[4][4] = {};
    const int nsteps = NPROD * nkt;

    {
        const unsigned short *aS, *bS;
        srcptr(0, aS, bS); stage(aS, bS, 0);
        srcptr(1, aS, bS); stage(aS, bS, 1);
    }
    wait_vm4();
    __builtin_amdgcn_s_barrier();
    __builtin_amdgcn_sched_barrier(0);
    loadFrags(0);

    for (int s = 0; s < nsteps; ++s) {
        if (s + 2 < nsteps) {
            const unsigned short *aS, *bS;
            srcptr(s + 2, aS, bS);
            stage(aS, bS, (s + 2) % 3);
        }
        __builtin_amdgcn_sched_barrier(0);
        __builtin_amdgcn_s_setprio(1);
#pragma unroll
        for (int m = 0; m < 4; ++m)
#pragma unroll
            for (int n = 0; n < 4; ++n)
                acc[m][n] = __builtin_amdgcn_mfma_f32_16x16x32_bf16(af[m], bfr[n], acc[m][n], 0, 0, 0);
        __builtin_amdgcn_s_setprio(0);
        __builtin_amdgcn_sched_barrier(0);
        if (s + 1 < nsteps) {
            if (s + 2 < nsteps) wait_vm4();
            else wait_vm0();
            __builtin_amdgcn_s_barrier();
            __builtin_amdgcn_sched_barrier(0);
            loadFrags((s + 1) % 3);
        }
    }

    const int cr = (lane >> 4) << 2, cc = lane & 15;
    if (WMODE == 0) {
        float* Cb = C + (long long)blockIdx.z * bsC;
#pragma unroll
        for (int m = 0; m < 4; ++m)
#pragma unroll
            for (int n = 0; n < 4; ++n) {
                const int gc = bx * 128 + wn + n * 16 + cc;
                const float badd = bias ? bias[gc] : 0.0f;
                const int gr0 = by * 128 + wm + m * 16 + cr;
#pragma unroll
                for (int i = 0; i < 4; ++i)
                    Cb[(long long)(gr0 + i) * ldC + gc] = acc[m][n][i] + badd;
            }
    } else {
        float* slab = (float*)sm;   // [2][16][132] fp32
        const int wmi = wv >> 1;
#pragma unroll
        for (int m = 0; m < 4; ++m) {
            __syncthreads();
#pragma unroll
            for (int n = 0; n < 4; ++n) {
                const int col = wn + n * 16 + cc;
                const float badd = bias ? bias[bx * 128 + col] : 0.0f;
#pragma unroll
                for (int i = 0; i < 4; ++i)
                    slab[(wmi * 16 + cr + i) * 132 + col] = acc[m][n][i] + badd;
            }
            __syncthreads();
            if (WMODE == 1) {
#pragma unroll
                for (int it = 0; it < 2; ++it) {
                    const int e = it * 256 + t;
                    const int wq = e >> 8, cg = (e >> 4) & 15, fr = e & 15;
                    const float* sp = slab + (wq * 16 + fr) * 132 + cg * 8;
                    const int rIn = wq * 64 + m * 16 + fr;
                    const int ktO = bx * 4 + (cg >> 2);
                    const int gO = cg & 3;
                    const long long base =
                        ((long long)by * outNkt + ktO) * 4096 + (gO * 128 + rIn) * 8;
                    unsigned short h[8], l[8];
#pragma unroll
                    for (int j = 0; j < 8; ++j) splitbf(sp[j], h[j], l[j]);
                    uint4 hp, lp;
                    hp.x = h[0] | ((unsigned)h[1] << 16); hp.y = h[2] | ((unsigned)h[3] << 16);
                    hp.z = h[4] | ((unsigned)h[5] << 16); hp.w = h[6] | ((unsigned)h[7] << 16);
                    lp.x = l[0] | ((unsigned)l[1] << 16); lp.y = l[2] | ((unsigned)l[3] << 16);
                    lp.z = l[4] | ((unsigned)l[5] << 16); lp.w = l[6] | ((unsigned)l[7] << 16);
                    *(uint4*)(imgH + base) = hp;
                    *(uint4*)(imgL + base) = lp;
                }
            } else {    // WMODE 3: vT image (B-layout over C^T), h only
#pragma unroll
                for (int it = 0; it < 2; ++it) {
                    const int e = it * 256 + t;
                    const int wq = e >> 8, s8 = (e >> 7) & 1, dl = e & 127;
                    const int sG = by * 128 + wq * 64 + m * 16 + s8 * 8;
                    const int z = sG >> 11, sIn = sG & 2047;
                    const int ktO = sIn >> 5, gO = (sIn >> 3) & 3;
                    const long long base =
                        ((long long)(z * 8 + bx) * 64 + ktO) * 4096 + (gO * 128 + dl) * 8;
                    unsigned short h[8];
#pragma unroll
                    for (int j = 0; j < 8; ++j)
                        h[j] = rne_bf(slab[(wq * 16 + s8 * 8 + j) * 132 + dl]);
                    uint4 hp;
                    hp.x = h[0] | ((unsigned)h[1] << 16); hp.y = h[2] | ((unsigned)h[3] << 16);
                    hp.z = h[4] | ((unsigned)h[5] << 16); hp.w = h[6] | ((unsigned)h[7] << 16);
                    *(uint4*)(imgH + base) = hp;
                }
            }
        }
    }
}

// ---------------------------------------------------------------------------
// softmax over rows of energy, in place; also emits bf16 A-image of attn.
// ---------------------------------------------------------------------------
__global__ __launch_bounds__(256) void softmax_img(
    float* __restrict__ attn, const int* __restrict__ mask,
    unsigned short* __restrict__ img)
{
    const int row = blockIdx.x;
    const int q = row & (S_LEN - 1);
    const int t = threadIdx.x;
    const int lane = t & 63, wid = t >> 6;
    float* rp = attn + (long long)row * S_LEN;
    const int* mp = mask + (long long)q * S_LEN;

    const float4 e0 = *(const float4*)(rp + t * 8);
    const float4 e1 = *(const float4*)(rp + t * 8 + 4);
    const int4 ma = *(const int4*)(mp + t * 8);
    const int4 mb = *(const int4*)(mp + t * 8 + 4);
    float zv[8];
    zv[0] = ma.x ? -e0.x : 1e9f;
    zv[1] = ma.y ? -e0.y : 1e9f;
    zv[2] = ma.z ? -e0.z : 1e9f;
    zv[3] = ma.w ? -e0.w : 1e9f;
    zv[4] = mb.x ? -e1.x : 1e9f;
    zv[5] = mb.y ? -e1.y : 1e9f;
    zv[6] = mb.z ? -e1.z : 1e9f;
    zv[7] = mb.w ? -e1.w : 1e9f;
    float mx = zv[0];
#pragma unroll
    for (int j = 1; j < 8; ++j) mx = fmaxf(mx, zv[j]);
#pragma unroll
    for (int o = 32; o > 0; o >>= 1) mx = fmaxf(mx, __shfl_xor(mx, o));
    __shared__ float redm[4], reds[4];
    if (lane == 0) redm[wid] = mx;
    __syncthreads();
    mx = fmaxf(fmaxf(redm[0], redm[1]), fmaxf(redm[2], redm[3]));
    float s = 0.f;
#pragma unroll
    for (int j = 0; j < 8; ++j) { zv[j] = expf(zv[j] - mx); s += zv[j]; }
#pragma unroll
    for (int o = 32; o > 0; o >>= 1) s += __shfl_xor(s, o);
    if (lane == 0) reds[wid] = s;
    __syncthreads();
    s = reds[0] + reds[1] + reds[2] + reds[3];
    const float inv = 1.0f / s;
    float4 o0, o1;
    o0.x = zv[0] * inv; o0.y = zv[1] * inv; o0.z = zv[2] * inv; o0.w = zv[3] * inv;
    o1.x = zv[4] * inv; o1.y = zv[5] * inv; o1.z = zv[6] * inv; o1.w = zv[7] * inv;
    *(float4*)(rp + t * 8) = o0;
    *(float4*)(rp + t * 8 + 4) = o1;
    const int z = row >> 11, rb = (row >> 7) & 15;
    const int ktO = t >> 2, gO = t & 3, r = row & 127;
    const long long base = (((long long)(z * 16 + rb) * 64 + ktO) * 512 + gO * 128 + r) * 8;
    uint4 hp;
    hp.x = rne_bf(o0.x) | ((unsigned)rne_bf(o0.y) << 16);
    hp.y = rne_bf(o0.z) | ((unsigned)rne_bf(o0.w) << 16);
    hp.z = rne_bf(o1.x) | ((unsigned)rne_bf(o1.y) << 16);
    hp.w = rne_bf(o1.z) | ((unsigned)rne_bf(o1.w) << 16);
    *(uint4*)(img + base) = hp;
}

// WqT[j][i] = Wq[i][j]  (1024x1024) — fallback path only
__global__ void transpose1024(const float* __restrict__ in, float* __restrict__ out)
{
    __shared__ float tile[32][33];
    const int bx = blockIdx.x << 5, by = blockIdx.y << 5;
    const int tx = threadIdx.x, ty = threadIdx.y;
#pragma unroll
    for (int i = 0; i < 4; ++i)
        tile[ty + 8 * i][tx] = in[(long long)(by + ty + 8 * i) * E_DIM + bx + tx];
    __syncthreads();
#pragma unroll
    for (int i = 0; i < 4; ++i)
        out[(long long)(bx + ty + 8 * i) * E_DIM + by + tx] = tile[tx][ty + 8 * i];
}

// t1[i] = dot(bq, We[i,:])  (= We . bq)
__global__ __launch_bounds__(256) void bias_c_kernel(
    const float* __restrict__ We, const float* __restrict__ bq, float* __restrict__ c)
{
    const int i = blockIdx.x;
    const int t = threadIdx.x;
    float s = 0.f;
    for (int d = t; d < E_DIM; d += 256) s += bq[d] * We[(long long)i * E_DIM + d];
#pragma unroll
    for (int o = 32; o > 0; o >>= 1) s += __shfl_xor(s, o);
    __shared__ float red[4];
    if ((t & 63) == 0) red[t >> 6] = s;
    __syncthreads();
    if (t == 0) c[i] = red[0] + red[1] + red[2] + red[3];
}

// ---------------------------------------------------------------------------
// FALLBACK path (round-1 proven), used only if ws_size is too small.
// ---------------------------------------------------------------------------
template <bool SPLIT, int WMODE>
__global__ __launch_bounds__(256) void gemm_split(
    const float* __restrict__ A, const float* __restrict__ B,
    float* __restrict__ C, const float* __restrict__ bias,
    int M, int N, int K,
    long long bsA, long long bsB, long long bsC)
{
    extern __shared__ unsigned short sm[];
    unsigned short* sAh = sm;
    unsigned short* sBh = sm + 5120;
    unsigned short* sAl = sm + 10240;
    unsigned short* sBl = sm + 15360;

    const int t = threadIdx.x;
    const int z = blockIdx.z;
    const float* Ab = A + (long long)z * bsA + (long long)blockIdx.y * 128 * K;
    const float* Bb = B + (long long)z * bsB + (long long)blockIdx.x * 128 * K;

    const int wv = t >> 6;
    const int lane = t & 63;
    const int wm = (wv >> 1) << 6;
    const int wn = (wv & 1) << 6;
    const int lr = lane & 15;
    const int ko = (lane >> 4) << 3;

    f32x4 acc[4][4] = {};

    for (int k0 = 0; k0 < K; k0 += 32) {
        __syncthreads();
#pragma unroll
        for (int i = 0; i < 4; ++i) {
            const int f = t + (i << 8);
            const int row = f >> 3;
            const int c4 = (f & 7) << 2;
            const float4 av = *(const float4*)(Ab + (long long)row * K + k0 + c4);
            const float4 bv = *(const float4*)(Bb + (long long)row * K + k0 + c4);
            if (SPLIT) {
                unsigned short h0, h1, h2, h3, l0, l1, l2, l3;
                splitbf(av.x, h0, l0); splitbf(av.y, h1, l1);
                splitbf(av.z, h2, l2); splitbf(av.w, h3, l3);
                uint2 hp, lp;
                hp.x = (unsigned)h0 | ((unsigned)h1 << 16);
                hp.y = (unsigned)h2 | ((unsigned)h3 << 16);
                lp.x = (unsigned)l0 | ((unsigned)l1 << 16);
                lp.y = (unsigned)l2 | ((unsigned)l3 << 16);
                *(uint2*)(sAh + row * 40 + c4) = hp;
                *(uint2*)(sAl + row * 40 + c4) = lp;
                splitbf(bv.x, h0, l0); splitbf(bv.y, h1, l1);
                splitbf(bv.z, h2, l2); splitbf(bv.w, h3, l3);
                hp.x = (unsigned)h0 | ((unsigned)h1 << 16);
                hp.y = (unsigned)h2 | ((unsigned)h3 << 16);
                lp.x = (unsigned)l0 | ((unsigned)l1 << 16);
                lp.y = (unsigned)l2 | ((unsigned)l3 << 16);
                *(uint2*)(sBh + row * 40 + c4) = hp;
                *(uint2*)(sBl + row * 40 + c4) = lp;
            } else {
                uint2 hp;
                hp.x = (unsigned)rne_bf(av.x) | ((unsigned)rne_bf(av.y) << 16);
                hp.y = (unsigned)rne_bf(av.z) | ((unsigned)rne_bf(av.w) << 16);
                *(uint2*)(sAh + row * 40 + c4) = hp;
                hp.x = (unsigned)rne_bf(bv.x) | ((unsigned)rne_bf(bv.y) << 16);
                hp.y = (unsigned)rne_bf(bv.z) | ((unsigned)rne_bf(bv.w) << 16);
                *(uint2*)(sBh + row * 40 + c4) = hp;
            }
        }
        __syncthreads();
        short8 ah[4], bh[4], al[4], bl[4];
#pragma unroll
        for (int m = 0; m < 4; ++m)
            ah[m] = *(const short8*)(sAh + (wm + m * 16 + lr) * 40 + ko);
#pragma unroll
        for (int n = 0; n < 4; ++n)
            bh[n] = *(const short8*)(sBh + (wn + n * 16 + lr) * 40 + ko);
        if (SPLIT) {
#pragma unroll
            for (int m = 0; m < 4; ++m)
                al[m] = *(const short8*)(sAl + (wm + m * 16 + lr) * 40 + ko);
#pragma unroll
            for (int n = 0; n < 4; ++n)
                bl[n] = *(const short8*)(sBl + (wn + n * 16 + lr) * 40 + ko);
        }
#pragma unroll
        for (int m = 0; m < 4; ++m) {
#pragma unroll
            for (int n = 0; n < 4; ++n) {
                acc[m][n] = __builtin_amdgcn_mfma_f32_16x16x32_bf16(ah[m], bh[n], acc[m][n], 0, 0, 0);
                if (SPLIT) {
                    acc[m][n] = __builtin_amdgcn_mfma_f32_16x16x32_bf16(ah[m], bl[n], acc[m][n], 0, 0, 0);
                    acc[m][n] = __builtin_amdgcn_mfma_f32_16x16x32_bf16(al[m], bh[n], acc[m][n], 0, 0, 0);
                }
            }
        }
    }

    const int cr = (lane >> 4) << 2;
    const int cc = lane & 15;
    float* Cb = C + (long long)z * bsC;
#pragma unroll
    for (int m = 0; m < 4; ++m) {
#pragma unroll
        for (int n = 0; n < 4; ++n) {
            const int gc = blockIdx.x * 128 + wn + n * 16 + cc;
            const float badd = bias ? bias[gc] : 0.0f;
            const int gr0 = blockIdx.y * 128 + wm + m * 16 + cr;
#pragma unroll
            for (int i = 0; i < 4; ++i) {
                const float val = acc[m][n][i] + badd;
                if (WMODE == 0) {
                    Cb[(long long)(gr0 + i) * N + gc] = val;
                } else {
                    const int r = gr0 + i;
                    Cb[(long long)(r >> 11) * ((long long)N * 2048) +
                       (long long)gc * 2048 + (r & 2047)] = val;
                }
            }
        }
    }
}

__global__ __launch_bounds__(256) void softmax_rows(
    float* __restrict__ attn, const int* __restrict__ mask)
{
    const int row = blockIdx.x;
    const int q = row & (S_LEN - 1);
    const int t = threadIdx.x;
    const int lane = t & 63, wid = t >> 6;
    float* rp = attn + (long long)row * S_LEN;
    const int* mp = mask + (long long)q * S_LEN;

    float zv[8];
    float mx = -3.4e38f;
#pragma unroll
    for (int j = 0; j < 8; ++j) {
        const int idx = t + (j << 8);
        const float e = rp[idx];
        const int mv = mp[idx];
        const float zz = (mv != 0) ? -e : 1e9f;
        zv[j] = zz;
        mx = fmaxf(mx, zz);
    }
#pragma unroll
    for (int o = 32; o > 0; o >>= 1) mx = fmaxf(mx, __shfl_xor(mx, o));
    __shared__ float redm[4], reds[4];
    if (lane == 0) redm[wid] = mx;
    __syncthreads();
    mx = fmaxf(fmaxf(redm[0], redm[1]), fmaxf(redm[2], redm[3]));

    float s = 0.f;
#pragma unroll
    for (int j = 0; j < 8; ++j) { zv[j] = expf(zv[j] - mx); s += zv[j]; }
#pragma unroll
    for (int o = 32; o > 0; o >>= 1) s += __shfl_xor(s, o);
    if (lane == 0) reds[wid] = s;
    __syncthreads();
    s = reds[0] + reds[1] + reds[2] + reds[3];
    const float inv = 1.0f / s;
#pragma unroll
    for (int j = 0; j < 8; ++j) rp[t + (j << 8)] = zv[j] * inv;
}

// ---------------------------------------------------------------------------
extern "C" void kernel_launch(void* const* d_in, const int* in_sizes, int n_in,
                              void* d_out, int out_size, void* d_ws, size_t ws_size,
                              hipStream_t stream)
{
    const float* query = (const float*)d_in[0];
    const float* key   = (const float*)d_in[1];
    const float* value = (const float*)d_in[2];
    const int*   mask  = (const int*)d_in[3];
    const float* Wq    = (const float*)d_in[4];
    const float* bq    = (const float*)d_in[5];
    const float* Wk    = (const float*)d_in[6];
    const float* bk    = (const float*)d_in[7];
    const float* Wv    = (const float*)d_in[8];
    const float* bv    = (const float*)d_in[9];
    const float* We    = (const float*)d_in[10];

    float* out  = (float*)d_out;
    float* attn = out + (long long)NB * S_LEN * E_DIM;

    // ---------------- ws layout (byte offsets) ----------------
    // small: t1 (4KB) | w (4KB) | r (64KB)  within first 128KB
    const size_t oT1   = 0;
    const size_t oW    = 4096;
    const size_t oR    = 8192;
    const size_t oWts  = 131072;                  // 9 x 2MB weight-image slots
    const size_t oWqTH = oWts + 0 * (2u << 20);
    const size_t oWqTL = oWts + 1 * (2u << 20);
    const size_t oWkTH = oWts + 2 * (2u << 20);
    const size_t oWkTL = oWts + 3 * (2u << 20);
    const size_t oWeH  = oWts + 4 * (2u << 20);   // -> GTH after PT GEMM
    const size_t oWeL  = oWts + 5 * (2u << 20);   // -> GTL
    const size_t oWvH  = oWts + 6 * (2u << 20);
    const size_t oPTH  = oWts + 7 * (2u << 20);
    const size_t oPTL  = oWts + 8 * (2u << 20);
    const size_t oBig1 = oWts + 9 * (2u << 20);   // qryH|qryL -> attnH (64MB)
    const size_t oBig2 = oBig1 + (64u << 20);     // keyH|keyL
    const size_t oBig3 = oBig2 + (64u << 20);     // qgH|qgL -> vTH|valH
    const size_t NEED  = oBig3 + (64u << 20);     // ~220 MB (< proven 224 MB)

    char* wsb = (char*)d_ws;

    if (ws_size >= NEED) {
        float* t1 = (float*)(wsb + oT1);
        float* wv = (float*)(wsb + oW);
        float* rv = (float*)(wsb + oR);
        unsigned short* WqTH = (unsigned short*)(wsb + oWqTH);
        unsigned short* WqTL = (unsigned short*)(wsb + oWqTL);
        unsigned short* WkTH = (unsigned short*)(wsb + oWkTH);
        unsigned short* WkTL = (unsigned short*)(wsb + oWkTL);
        unsigned short* WeH  = (unsigned short*)(wsb + oWeH);
        unsigned short* WeL  = (unsigned short*)(wsb + oWeL);
        unsigned short* GTH  = (unsigned short*)(wsb + oWeH);   // alias (We dead)
        unsigned short* GTL  = (unsigned short*)(wsb + oWeL);   // alias
        unsigned short* WvH  = (unsigned short*)(wsb + oWvH);
        unsigned short* PTH  = (unsigned short*)(wsb + oPTH);
        unsigned short* PTL  = (unsigned short*)(wsb + oPTL);
        unsigned short* qryH = (unsigned short*)(wsb + oBig1);
        unsigned short* qryL = (unsigned short*)(wsb + oBig1 + (32u << 20));
        unsigned short* attnH = (unsigned short*)(wsb + oBig1);           // alias
        unsigned short* keyH = (unsigned short*)(wsb + oBig2);
        unsigned short* keyL = (unsigned short*)(wsb + oBig2 + (32u << 20));
        unsigned short* qgH  = (unsigned short*)(wsb + oBig3);
        unsigned short* qgL  = (unsigned short*)(wsb + oBig3 + (32u << 20));
        unsigned short* vTH  = (unsigned short*)(wsb + oBig3);            // alias
        unsigned short* valH = (unsigned short*)(wsb + oBig3 + (32u << 20));

        // bias path: t1 = We.bq ; w = Wk^T.t1 ; r = key.w  (zeros here)
        bias_c_kernel<<<1024, 256, 0, stream>>>(We, bq, t1);
        wvecT_kernel<<<4, 256, 0, stream>>>(Wk, t1, wv);
        rvec_kernel<<<NB * S_LEN, 256, 0, stream>>>(key, wv, rv);

        conv_imgT<<<dim3(32, 8), 256, 0, stream>>>(Wq, WqTH, WqTL, 32);
        conv_imgT<<<dim3(32, 8), 256, 0, stream>>>(Wk, WkTH, WkTL, 32);
        conv_img<true><<<dim3(32, 8), 256, 0, stream>>>(We, WeH, WeL, 1024, 32);
        conv_img<false><<<dim3(32, 8), 256, 0, stream>>>(Wv, WvH, nullptr, 1024, 32);
        conv_img<true><<<dim3(32, 128), 256, 0, stream>>>(query, qryH, qryL, 1024, 32);
        conv_img<true><<<dim3(32, 128), 256, 0, stream>>>(key, keyH, keyL, 1024, 32);

        // PT = Wq^T @ We^T  (A=WqT, B=We)  -> PTH/PTL
        gemm_img<3, 1><<<dim3(8, 8, 1), 256, 49152, stream>>>(
            WqTH, WqTL, WeH, WeL, nullptr, nullptr, PTH, PTL, 0, 0, 32, 0, 0, 32);
        // GT = Wk^T @ PT^T = G^T  (A=WkT, B=PT) -> GTH/GTL (over dead We slots)
        gemm_img<3, 1><<<dim3(8, 8, 1), 256, 49152, stream>>>(
            WkTH, WkTL, PTH, PTL, nullptr, nullptr, GTH, GTL, 0, 0, 32, 0, 0, 32);
        // qg = query @ GT^T = query.G  -> qg images in Big3
        gemm_img<3, 1><<<dim3(8, 128, 1), 256, 49152, stream>>>(
            qryH, qryL, GTH, GTL, nullptr, nullptr, qgH, qgL, 0, 0, 32, 0, 0, 32);
        // energy = qg @ key^T + r[col]  -> attn region (fp32 scratch)
        gemm_e3<<<dim3(16, 8, NB), 512, 0, stream>>>(
            qgH, qgL, keyH, keyL, rv, attn,
            2048, (long long)S_LEN * S_LEN, 32, 16, 16);
        // value image (over dead qgL), then v-proj -> vT image (over dead qgH)
        conv_img<false><<<dim3(32, 128), 256, 0, stream>>>(value, valH, nullptr, 1024, 32);
        gemm_img<1, 3><<<dim3(8, 128, 1), 256, 49152, stream>>>(
            valH, nullptr, WvH, nullptr, nullptr, bv, vTH, nullptr, 0, 0, 32, 0, 0, 0);
        // softmax in place + attn bf16 image (over dead qry images)
        softmax_img<<<NB * S_LEN, 256, 0, stream>>>(attn, mask, attnH);
        // out = attn @ v per batch
        gemm_big<1><<<dim3(8, 8, NB), 512, 0, stream>>>(
            attnH, nullptr, vTH, nullptr, out, nullptr,
            1024, (long long)S_LEN * E_DIM, 64, 16, 8);
    } else {
        float* ws   = (float*)d_ws;
        float* WqT  = ws;
        float* P    = WqT + 1048576;
        float* cvec = P + 1048576;
        float* kbuf = cvec + 1024;
        float* qw   = kbuf + 16777216;
        float* vT   = qw + 16777216;
        const size_t need_old = (size_t)(1048576 * 2 + 1024 + 16777216 * 3) * 4;
        if (ws_size < need_old) return;

        transpose1024<<<dim3(32, 32), dim3(32, 8), 0, stream>>>(Wq, WqT);
        bias_c_kernel<<<1024, 256, 0, stream>>>(We, bq, cvec);
        gemm_split<true, 0><<<dim3(8, 8, 1), 256, 40960, stream>>>(
            We, WqT, P, nullptr, 1024, 1024, 1024, 0, 0, 0);
        gemm_split<true, 0><<<dim3(8, 128, 1), 256, 40960, stream>>>(
            key, Wk, kbuf, bk, 16384, 1024, 1024, 0, 0, 0);
        gemm_split<false, 1><<<dim3(8, 128, 1), 256, 20480, stream>>>(
            value, Wv, vT, bv, 16384, 1024, 1024, 0, 0, 0);
        gemm_split<true, 0><<<dim3(8, 128, 1), 256, 40960, stream>>>(
            query, P, qw, cvec, 16384, 1024, 1024, 0, 0, 0);
        gemm_split<true, 0><<<dim3(16, 16, NB), 256, 40960, stream>>>(
            qw, kbuf, attn, nullptr, 2048, 2048, 1024,
            (long long)S_LEN * E_DIM, (long long)S_LEN * E_DIM, (long long)S_LEN * S_LEN);
        softmax_rows<<<NB * S_LEN, 256, 0, stream>>>(attn, mask);
        gemm_split<false, 0><<<dim3(8, 16, NB), 256, 20480, stream>>>(
            attn, vT, out, nullptr, 2048, 1024, 2048,
            (long long)S_LEN * S_LEN, (long long)E_DIM * S_LEN, (long long)S_LEN * E_DIM);
    }

    (void)in_sizes; (void)n_in; (void)out_size;
}

// Round 12
// 731.102 us; speedup vs baseline: 5.2108x; 1.0511x over previous
//
#include <hip/hip_runtime.h>

// ---------------------------------------------------------------------------
// EBMAttention (B=8, S=2048, E=1024, H=1), fp32 in/out.
// Round 12: overhead cleanup on the round-11 folded pipeline:
//   - wvec2: parallel Wk^T.t1 (64 blocks, coalesced, atomicAdd; w pre-zeroed)
//     replacing the 4-block latency-bound wvecT (~30us -> ~3us).
//   - merged dispatches: {Wq,Wk} transpose-convs in one grid.z=2 launch;
//     {query,key} big convs in one grid.z=2 launch.
// Hot kernels (gemm_e3 / gemm_big / gemm_img / softmax) byte-identical.
// Pipeline: PT = Wq^T.We^T, GT = Wk^T.PT^T = G^T, qg = query.G,
//   energy = qg.key^T + r[col]  (r = key.(Wk^T.We.bq), zero here),
//   attn = softmax(-energy) (mask); v = value.Wv^T; out = attn.v
// Pre-softmax GEMMs: 3-product hi/lo bf16 split (near-fp32 via MFMA).
// Operands are pre-tiled bf16 "LDS-images": per 128x32 tile, 16B chunk
// c = g*128 + r holds X[r][kt*32+g*8 .. +7].
// ---------------------------------------------------------------------------

typedef __attribute__((ext_vector_type(8))) short short8;
typedef __attribute__((ext_vector_type(4))) float f32x4;
typedef __attribute__((ext_vector_type(16))) float f32x16;

#define E_DIM 1024
#define S_LEN 2048
#define NB 8

// round-to-nearest-even fp32 -> bf16 bits
__device__ __forceinline__ unsigned short rne_bf(float x) {
    unsigned int u = __float_as_uint(x);
    return (unsigned short)((u + 0x7fffu + ((u >> 16) & 1u)) >> 16);
}

__device__ __forceinline__ void splitbf(float x, unsigned short& h, unsigned short& l) {
    unsigned int u = __float_as_uint(x);
    unsigned int rh = ((u + 0x7fffu + ((u >> 16) & 1u)) >> 16) << 16;
    h = (unsigned short)(rh >> 16);
    float r = x - __uint_as_float(rh);
    unsigned int v = __float_as_uint(r);
    l = (unsigned short)((v + 0x7fffu + ((v >> 16) & 1u)) >> 16);
}

__device__ __forceinline__ void lds_cp16(const void* g, void* l) {
    __builtin_amdgcn_global_load_lds(
        (const __attribute__((address_space(1))) unsigned int*)g,
        (__attribute__((address_space(3))) unsigned int*)l, 16, 0, 0);
}

__device__ __forceinline__ void wait_vm6() { asm volatile("s_waitcnt vmcnt(6)" ::: "memory"); }
__device__ __forceinline__ void wait_vm4() { asm volatile("s_waitcnt vmcnt(4)" ::: "memory"); }
__device__ __forceinline__ void wait_vm3() { asm volatile("s_waitcnt vmcnt(3)" ::: "memory"); }
__device__ __forceinline__ void wait_vm0() { asm volatile("s_waitcnt vmcnt(0)" ::: "memory"); }

// Bijective XCD-aware swizzle of (bx,by) within a z-plane.
__device__ __forceinline__ void swizzle_xy(int& bx, int& by) {
    const int gx = gridDim.x, gy = gridDim.y;
    const int nwg = gx * gy;
    const int w = by * gx + bx;
    if ((gx & 3) == 0 && (gy & 3) == 0 && (((gx >> 2) * (gy >> 2)) & 7) == 0) {
        const int nchx = gx >> 2;
        const int xcd = w & 7, i = w >> 3;
        const int j = i >> 4, p = i & 15;
        const int ch = xcd + 8 * j;
        const int chy = ch / nchx, chx = ch - chy * nchx;
        by = chy * 4 + (p >> 2);
        bx = chx * 4 + (p & 3);
    } else if ((nwg & 7) == 0) {
        const int cpx = nwg >> 3;
        const int sw = (w & 7) * cpx + (w >> 3);
        bx = sw % gx;
        by = sw / gx;
    }
}

// ---------------------------------------------------------------------------
// conv_img: fp32 [R x K] row-major -> h-image (+ l-image).  grid=(K/32, R/128)
// ---------------------------------------------------------------------------
template <bool DO_L>
__global__ __launch_bounds__(256) void conv_img(
    const float* __restrict__ src, unsigned short* __restrict__ h,
    unsigned short* __restrict__ l, int ld, int nkt)
{
    const int t = threadIdx.x;
    const long long tb = ((long long)blockIdx.y * nkt + blockIdx.x) * 4096;
    const float* s0 = src + (long long)blockIdx.y * 128 * ld + blockIdx.x * 32;
#pragma unroll
    for (int i = 0; i < 4; ++i) {
        const int f = i * 256 + t;
        const int r = f >> 3;
        const int c4 = (f & 7) << 2;
        const float4 v = *(const float4*)(s0 + (long long)r * ld + c4);
        const int gg = c4 >> 3;
        const int half = (c4 >> 2) & 1;
        const long long wo = tb + (long long)(gg * 128 + r) * 8 + half * 4;
        unsigned short h0, h1, h2, h3;
        if (DO_L) {
            unsigned short l0, l1, l2, l3;
            splitbf(v.x, h0, l0); splitbf(v.y, h1, l1);
            splitbf(v.z, h2, l2); splitbf(v.w, h3, l3);
            uint2 hp, lp;
            hp.x = h0 | ((unsigned)h1 << 16); hp.y = h2 | ((unsigned)h3 << 16);
            lp.x = l0 | ((unsigned)l1 << 16); lp.y = l2 | ((unsigned)l3 << 16);
            *(uint2*)(h + wo) = hp;
            *(uint2*)(l + wo) = lp;
        } else {
            h0 = rne_bf(v.x); h1 = rne_bf(v.y); h2 = rne_bf(v.z); h3 = rne_bf(v.w);
            uint2 hp;
            hp.x = h0 | ((unsigned)h1 << 16); hp.y = h2 | ((unsigned)h3 << 16);
            *(uint2*)(h + wo) = hp;
        }
    }
}

// merged query/key conv: grid (32,128,2); z=0 -> A set, z=1 -> B set (h+l).
__global__ __launch_bounds__(256) void conv_img2(
    const float* __restrict__ srcA, const float* __restrict__ srcB,
    unsigned short* __restrict__ hA, unsigned short* __restrict__ lA,
    unsigned short* __restrict__ hB, unsigned short* __restrict__ lB, int nkt)
{
    const float* src = blockIdx.z ? srcB : srcA;
    unsigned short* h = blockIdx.z ? hB : hA;
    unsigned short* l = blockIdx.z ? lB : lA;
    const int t = threadIdx.x;
    const long long tb = ((long long)blockIdx.y * nkt + blockIdx.x) * 4096;
    const float* s0 = src + (long long)blockIdx.y * 128 * E_DIM + blockIdx.x * 32;
#pragma unroll
    for (int i = 0; i < 4; ++i) {
        const int f = i * 256 + t;
        const int r = f >> 3;
        const int c4 = (f & 7) << 2;
        const float4 v = *(const float4*)(s0 + (long long)r * E_DIM + c4);
        const int gg = c4 >> 3;
        const int half = (c4 >> 2) & 1;
        const long long wo = tb + (long long)(gg * 128 + r) * 8 + half * 4;
        unsigned short h0, h1, h2, h3, l0, l1, l2, l3;
        splitbf(v.x, h0, l0); splitbf(v.y, h1, l1);
        splitbf(v.z, h2, l2); splitbf(v.w, h3, l3);
        uint2 hp, lp;
        hp.x = h0 | ((unsigned)h1 << 16); hp.y = h2 | ((unsigned)h3 << 16);
        lp.x = l0 | ((unsigned)l1 << 16); lp.y = l2 | ((unsigned)l3 << 16);
        *(uint2*)(h + wo) = hp;
        *(uint2*)(l + wo) = lp;
    }
}

// ---------------------------------------------------------------------------
// conv_imgT2: emit h+l images of src^T for TWO 1024x1024 matrices in one
// dispatch.  grid = (nkt=32, 8, 2); z selects {srcA->imgsA, srcB->imgsB}.
// ---------------------------------------------------------------------------
__global__ __launch_bounds__(256) void conv_imgT2(
    const float* __restrict__ srcA, const float* __restrict__ srcB,
    unsigned short* __restrict__ hA, unsigned short* __restrict__ lA,
    unsigned short* __restrict__ hB, unsigned short* __restrict__ lB, int nkt)
{
    __shared__ float tile[32][132];
    const float* src = blockIdx.z ? srcB : srcA;
    unsigned short* h = blockIdx.z ? hB : hA;
    unsigned short* l = blockIdx.z ? lB : lA;
    const int t = threadIdx.x;
    const int kt = blockIdx.x;
    const int rb = blockIdx.y;
    const float* s0 = src + (long long)kt * 32 * E_DIM + rb * 128;
#pragma unroll
    for (int i = 0; i < 4; ++i) {
        const int f = i * 256 + t;
        const int r = f >> 5;
        const int c4 = (f & 31) << 2;
        const float4 v = *(const float4*)(s0 + (long long)r * E_DIM + c4);
        tile[r][c4] = v.x; tile[r][c4 + 1] = v.y;
        tile[r][c4 + 2] = v.z; tile[r][c4 + 3] = v.w;
    }
    __syncthreads();
    const long long tb = ((long long)rb * nkt + kt) * 4096;
#pragma unroll
    for (int i = 0; i < 2; ++i) {
        const int c = i * 256 + t;
        const int g = c >> 7, r = c & 127;
        unsigned short hh[8], ll[8];
#pragma unroll
        for (int j = 0; j < 8; ++j) splitbf(tile[g * 8 + j][r], hh[j], ll[j]);
        uint4 hp, lp;
        hp.x = hh[0] | ((unsigned)hh[1] << 16); hp.y = hh[2] | ((unsigned)hh[3] << 16);
        hp.z = hh[4] | ((unsigned)hh[5] << 16); hp.w = hh[6] | ((unsigned)hh[7] << 16);
        lp.x = ll[0] | ((unsigned)ll[1] << 16); lp.y = ll[2] | ((unsigned)ll[3] << 16);
        lp.z = ll[4] | ((unsigned)ll[5] << 16); lp.w = ll[6] | ((unsigned)ll[7] << 16);
        *(uint4*)(h + tb + (long long)c * 8) = hp;
        *(uint4*)(l + tb + (long long)c * 8) = lp;
    }
}

// w += Wk^T . t1, parallel: grid 64, block 256.  Block b covers rows
// [b*16, b*16+16); thread t accumulates 4 columns {t, t+256, t+512, t+768};
// atomicAdd finish.  REQUIRES w pre-zeroed (hipMemsetAsync).
__global__ __launch_bounds__(256) void wvec2_kernel(
    const float* __restrict__ Wk, const float* __restrict__ t1, float* __restrict__ w)
{
    const int t = threadIdx.x;
    float acc0 = 0.f, acc1 = 0.f, acc2 = 0.f, acc3 = 0.f;
#pragma unroll
    for (int j = 0; j < 16; ++j) {
        const int d = blockIdx.x * 16 + j;
        const float tv = t1[d];
        const float* row = Wk + (long long)d * E_DIM;
        acc0 += tv * row[t];
        acc1 += tv * row[t + 256];
        acc2 += tv * row[t + 512];
        acc3 += tv * row[t + 768];
    }
    atomicAdd(&w[t], acc0);
    atomicAdd(&w[t + 256], acc1);
    atomicAdd(&w[t + 512], acc2);
    atomicAdd(&w[t + 768], acc3);
}

// r[row] = key[row,:] . w   over B*S rows
__global__ __launch_bounds__(256) void rvec_kernel(
    const float* __restrict__ key, const float* __restrict__ w, float* __restrict__ r)
{
    const int row = blockIdx.x;
    const int t = threadIdx.x;
    const float4 kv = ((const float4*)(key + (long long)row * E_DIM))[t];
    const float4 wv = ((const float4*)w)[t];
    float s = kv.x * wv.x + kv.y * wv.y + kv.z * wv.z + kv.w * wv.w;
#pragma unroll
    for (int o = 32; o > 0; o >>= 1) s += __shfl_xor(s, o);
    __shared__ float red[4];
    if ((t & 63) == 0) red[t >> 6] = s;
    __syncthreads();
    if (t == 0) r[row] = red[0] + red[1] + red[2] + red[3];
}

// ---------------------------------------------------------------------------
// gemm_e3: energy GEMM, seg-interleaved 3-product split + column bias r.
// C[2048,2048] per z = A(qg) @ B(key)^T + r[z*2048+col], fp32 out.
// 256x128 tile, BK=16, 8 waves (wave tile 64x64 = 2x2 of 32x32 MFMA).
// Ring-3 x 24KB (72KB LDS), launch_bounds(512,4)  [DO NOT raise: rnd-9 spill]
// ---------------------------------------------------------------------------
__global__ __launch_bounds__(512, 4) void gemm_e3(
    const unsigned short* __restrict__ Ah, const unsigned short* __restrict__ Al,
    const unsigned short* __restrict__ Bh, const unsigned short* __restrict__ Bl,
    const float* __restrict__ rbias,
    float* __restrict__ C, int ldC, long long bsC, int nkt32, int aZrb, int bZrb)
{
    __shared__ unsigned short smb[36864];   // 3 x 24KB

    const int t = threadIdx.x;
    const int wv = t >> 6, lane = t & 63;
    const int wr = wv >> 1, wc = wv & 1;
    const int l31 = lane & 31, lh = lane >> 5;

    int bx = blockIdx.x, by = blockIdx.y;
    swizzle_xy(bx, by);

    const long long aB0 = ((long long)blockIdx.z * aZrb + 2 * by) * nkt32 * 4096;
    const long long aB1 = aB0 + (long long)nkt32 * 4096;
    const long long bB0 = ((long long)blockIdx.z * bZrb + bx) * nkt32 * 4096;

    const int rA = t & 255, glA = t >> 8;
    const int bc = t & 255;
    auto stage = [&](int k16, int c) {
        unsigned short* buf = smb + c * 12288;
        const int kt32 = k16 >> 1, hh = k16 & 1;
        const long long aOff = ((rA >> 7) ? aB1 : aB0) + (long long)kt32 * 4096
                             + ((2 * hh + glA) * 128 + (rA & 127)) * 8;
        lds_cp16(Ah + aOff, buf + t * 8);
        lds_cp16(Al + aOff, buf + 4096 + t * 8);
        const long long bOff = bB0 + (long long)kt32 * 4096
                             + ((2 * hh + (bc >> 7)) * 128 + (bc & 127)) * 8;
        const unsigned short* bsrc = (t < 256) ? Bh : Bl;   // wave-uniform
        lds_cp16(bsrc + bOff, buf + 8192 + t * 8);
    };

    short8 ah[2], al[2], bh[2], bl[2];
    auto loadFrags = [&](int c) {
        const unsigned short* buf = smb + c * 12288;
#pragma unroll
        for (int m = 0; m < 2; ++m) {
            const int ra = lh * 256 + wr * 64 + m * 32 + l31;
            ah[m] = *(const short8*)(buf + ra * 8);
            al[m] = *(const short8*)(buf + 4096 + ra * 8);
        }
#pragma unroll
        for (int n = 0; n < 2; ++n) {
            const int rb = lh * 128 + wc * 64 + n * 32 + l31;
            bh[n] = *(const short8*)(buf + 8192 + rb * 8);
            bl[n] = *(const short8*)(buf + 10240 + rb * 8);
        }
    };

    f32x16 acc[2][2] = {};
    const int n16 = nkt32 * 2;

    stage(0, 0);
    stage(1, 1);

    for (int s = 0; s < n16; ++s) {
        __builtin_amdgcn_s_barrier();           // protect buf[(s+2)%3]
        if (s + 2 < n16) {
            stage(s + 2, (s + 2) % 3);
            wait_vm6();                          // own stage(s) landed
        } else if (s + 1 < n16) {
            wait_vm3();
        } else {
            wait_vm0();
        }
        __builtin_amdgcn_s_barrier();           // all waves' stage(s) landed
        __builtin_amdgcn_sched_barrier(0);
        loadFrags(s % 3);
        __builtin_amdgcn_s_setprio(1);
#pragma unroll
        for (int m = 0; m < 2; ++m)
#pragma unroll
            for (int n = 0; n < 2; ++n)
                acc[m][n] = __builtin_amdgcn_mfma_f32_32x32x16_bf16(ah[m], bh[n], acc[m][n], 0, 0, 0);
#pragma unroll
        for (int m = 0; m < 2; ++m)
#pragma unroll
            for (int n = 0; n < 2; ++n)
                acc[m][n] = __builtin_amdgcn_mfma_f32_32x32x16_bf16(al[m], bh[n], acc[m][n], 0, 0, 0);
#pragma unroll
        for (int m = 0; m < 2; ++m)
#pragma unroll
            for (int n = 0; n < 2; ++n)
                acc[m][n] = __builtin_amdgcn_mfma_f32_32x32x16_bf16(ah[m], bl[n], acc[m][n], 0, 0, 0);
        __builtin_amdgcn_s_setprio(0);
    }

    // 32x32 C/D layout: col = lane&31, row = (reg&3) + 8*(reg>>2) + 4*(lane>>5)
    float* Cb = C + (long long)blockIdx.z * bsC;
#pragma unroll
    for (int m = 0; m < 2; ++m)
#pragma unroll
        for (int n = 0; n < 2; ++n) {
            const int gc = bx * 128 + wc * 64 + n * 32 + l31;
            const float rb = rbias ? rbias[(long long)blockIdx.z * 2048 + gc] : 0.0f;
            const int gr0 = by * 256 + wr * 64 + m * 32 + 4 * lh;
#pragma unroll
            for (int reg = 0; reg < 16; ++reg) {
                const int row = (reg & 3) + 8 * (reg >> 2);
                Cb[(long long)(gr0 + row) * ldC + gc] = acc[m][n][reg] + rb;
            }
        }
}

// ---------------------------------------------------------------------------
// gemm_big: 256x128 tile, 8 waves — used for the out-GEMM (NPROD=1).
// Round-7 single-barrier ring + register prefetch (unchanged).
// ---------------------------------------------------------------------------
template <int NPROD>
__global__ __launch_bounds__(512, 4) void gemm_big(
    const unsigned short* __restrict__ Ah, const unsigned short* __restrict__ Al,
    const unsigned short* __restrict__ Bh, const unsigned short* __restrict__ Bl,
    float* __restrict__ C, const float* __restrict__ bias,
    int ldC, long long bsC, int nkt, int aZrb, int bZrb)
{
    __shared__ unsigned short smb[36864];

    const int t = threadIdx.x;
    const int wv = t >> 6, lane = t & 63;
    const int wr = wv >> 1, wc = wv & 1;
    const int lr = lane & 15, gq = lane >> 4;

    int bx = blockIdx.x, by = blockIdx.y;
    swizzle_xy(bx, by);

    const long long aB0 = ((long long)blockIdx.z * aZrb + 2 * by) * nkt * 4096;
    const long long aB1 = aB0 + (long long)nkt * 4096;
    const long long bB0 = ((long long)blockIdx.z * bZrb + bx) * nkt * 4096;

    auto srcptr = [&](int s, const unsigned short*& a0, const unsigned short*& a1,
                      const unsigned short*& bS) {
        int seg, kt;
        if (NPROD == 3) {
            seg = (s >= 2 * nkt) ? 2 : (s >= nkt ? 1 : 0);
            kt = s - seg * nkt;
        } else { seg = 0; kt = s; }
        const unsigned short* aBase = ((NPROD == 3 && seg == 1) ? Al : Ah);
        const unsigned short* bBase = ((NPROD == 3 && seg == 2) ? Bl : Bh);
        a0 = aBase + aB0 + (long long)kt * 4096;
        a1 = aBase + aB1 + (long long)kt * 4096;
        bS = bBase + bB0 + (long long)kt * 4096;
    };
    auto stage = [&](const unsigned short* a0, const unsigned short* a1,
                     const unsigned short* bS, int c) {
        unsigned short* dA = smb + c * 12288;
        lds_cp16(a0 + t * 8, dA + t * 8);
        lds_cp16(a1 + t * 8, dA + 4096 + t * 8);
        lds_cp16(bS + t * 8, dA + 8192 + t * 8);
    };

    short8 af[4], bfr[4];
    auto loadFrags = [&](int c) {
        const unsigned short* dA = smb + c * 12288;
        const unsigned short* dB = dA + 8192;
#pragma unroll
        for (int m = 0; m < 4; ++m) {
            const int R = wr * 64 + m * 16 + lr;
            af[m] = *(const short8*)(dA + (R >> 7) * 4096 + (gq * 128 + (R & 127)) * 8);
        }
#pragma unroll
        for (int n = 0; n < 4; ++n) {
            const int Cc = wc * 64 + n * 16 + lr;
            bfr[n] = *(const short8*)(dB + (gq * 128 + Cc) * 8);
        }
    };

    f32x4 acc[4][4] = {};
    const int nsteps = NPROD * nkt;

    {
        const unsigned short *a0, *a1, *bS;
        srcptr(0, a0, a1, bS); stage(a0, a1, bS, 0);
        srcptr(1, a0, a1, bS); stage(a0, a1, bS, 1);
    }
    wait_vm3();
    __builtin_amdgcn_s_barrier();
    __builtin_amdgcn_sched_barrier(0);
    loadFrags(0);

    for (int s = 0; s < nsteps; ++s) {
        if (s + 2 < nsteps) {
            const unsigned short *a0, *a1, *bS;
            srcptr(s + 2, a0, a1, bS);
            stage(a0, a1, bS, (s + 2) % 3);
        }
        __builtin_amdgcn_sched_barrier(0);
        __builtin_amdgcn_s_setprio(1);
#pragma unroll
        for (int m = 0; m < 4; ++m)
#pragma unroll
            for (int n = 0; n < 4; ++n)
                acc[m][n] = __builtin_amdgcn_mfma_f32_16x16x32_bf16(af[m], bfr[n], acc[m][n], 0, 0, 0);
        __builtin_amdgcn_s_setprio(0);
        __builtin_amdgcn_sched_barrier(0);
        if (s + 1 < nsteps) {
            if (s + 2 < nsteps) wait_vm3();
            else wait_vm0();
            __builtin_amdgcn_s_barrier();
            __builtin_amdgcn_sched_barrier(0);
            loadFrags((s + 1) % 3);
        }
    }

    const int cr = (lane >> 4) << 2, cc = lane & 15;
    float* Cb = C + (long long)blockIdx.z * bsC;
#pragma unroll
    for (int m = 0; m < 4; ++m)
#pragma unroll
        for (int n = 0; n < 4; ++n) {
            const int gc = bx * 128 + wc * 64 + n * 16 + cc;
            const float badd = bias ? bias[gc] : 0.0f;
            const int gr0 = by * 256 + wr * 64 + m * 16 + cr;
#pragma unroll
            for (int i = 0; i < 4; ++i)
                Cb[(long long)(gr0 + i) * ldC + gc] = acc[m][n][i] + badd;
        }
}

// ---------------------------------------------------------------------------
// gemm_img: 128x128, 4 waves — image-emitting variants (WMODE 1 / 3).
// Round-7 structure (unchanged).  Dyn LDS 49152 B.
// ---------------------------------------------------------------------------
template <int NPROD, int WMODE>
__global__ __launch_bounds__(256) void gemm_img(
    const unsigned short* __restrict__ Ah, const unsigned short* __restrict__ Al,
    const unsigned short* __restrict__ Bh, const unsigned short* __restrict__ Bl,
    float* __restrict__ C, const float* __restrict__ bias,
    unsigned short* __restrict__ imgH, unsigned short* __restrict__ imgL,
    int ldC, long long bsC, int nkt, int aZrb, int bZrb, int outNkt)
{
    extern __shared__ unsigned short sm[];

    const int t = threadIdx.x;
    const int wv = t >> 6, lane = t & 63;
    const int wm = (wv >> 1) << 6, wn = (wv & 1) << 6;
    const int lr = lane & 15, gq = lane >> 4;

    int bx = blockIdx.x, by = blockIdx.y;
    swizzle_xy(bx, by);

    const long long aB0 = ((long long)blockIdx.z * aZrb + by) * nkt * 4096;
    const long long bB0 = ((long long)blockIdx.z * bZrb + bx) * nkt * 4096;

    auto srcptr = [&](int s, const unsigned short*& aS, const unsigned short*& bS) {
        int seg, kt;
        if (NPROD == 3) {
            seg = (s >= 2 * nkt) ? 2 : (s >= nkt ? 1 : 0);
            kt = s - seg * nkt;
        } else { seg = 0; kt = s; }
        aS = ((NPROD == 3 && seg == 1) ? Al : Ah) + aB0 + (long long)kt * 4096;
        bS = ((NPROD == 3 && seg == 2) ? Bl : Bh) + bB0 + (long long)kt * 4096;
    };
    auto stage = [&](const unsigned short* aS, const unsigned short* bS, int c) {
        unsigned short* dA = sm + c * 8192;
        unsigned short* dB = dA + 4096;
#pragma unroll
        for (int j = 0; j < 2; ++j) {
            lds_cp16(aS + (wv * 128 + j * 64 + lane) * 8, dA + (wv * 128 + j * 64) * 8);
            lds_cp16(bS + (wv * 128 + j * 64 + lane) * 8, dB + (wv * 128 + j * 64) * 8);
        }
    };

    short8 af[4], bfr[4];
    auto loadFrags = [&](int c) {
        const unsigned short* smA = sm + c * 8192;
        const unsigned short* smB = smA + 4096;
        const unsigned short* pa = smA + (gq * 128 + wm + lr) * 8;
        const unsigned short* pb = smB + (gq * 128 + wn + lr) * 8;
#pragma unroll
        for (int m = 0; m < 4; ++m) af[m] = *(const short8*)(pa + m * 128);
#pragma unroll
        for (int n = 0; n < 4; ++n) bfr[n] = *(const short8*)(pb + n * 128);
    };

    f32x4 acc[4][4] = {};
    const int nsteps = NPROD * nkt;

    {
        const unsigned short *aS, *bS;
        srcptr(0, aS, bS); stage(aS, bS, 0);
        srcptr(1, aS, bS); stage(aS, bS, 1);
    }
    wait_vm4();
    __builtin_amdgcn_s_barrier();
    __builtin_amdgcn_sched_barrier(0);
    loadFrags(0);

    for (int s = 0; s < nsteps; ++s) {
        if (s + 2 < nsteps) {
            const unsigned short *aS, *bS;
            srcptr(s + 2, aS, bS);
            stage(aS, bS, (s + 2) % 3);
        }
        __builtin_amdgcn_sched_barrier(0);
        __builtin_amdgcn_s_setprio(1);
#pragma unroll
        for (int m = 0; m < 4; ++m)
#pragma unroll
            for (int n = 0; n < 4; ++n)
                acc[m][n] = __builtin_amdgcn_mfma_f32_16x16x32_bf16(af[m], bfr[n], acc[m][n], 0, 0, 0);
        __builtin_amdgcn_s_setprio(0);
        __builtin_amdgcn_sched_barrier(0);
        if (s + 1 < nsteps) {
            if (s + 2 < nsteps) wait_vm4();
            else wait_vm0();
            __builtin_amdgcn_s_barrier();
            __builtin_amdgcn_sched_barrier(0);
            loadFrags((s + 1) % 3);
        }
    }

    const int cr = (lane >> 4) << 2, cc = lane & 15;
    if (WMODE == 0) {
        float* Cb = C + (long long)blockIdx.z * bsC;
#pragma unroll
        for (int m = 0; m < 4; ++m)
#pragma unroll
            for (int n = 0; n < 4; ++n) {
                const int gc = bx * 128 + wn + n * 16 + cc;
                const float badd = bias ? bias[gc] : 0.0f;
                const int gr0 = by * 128 + wm + m * 16 + cr;
#pragma unroll
                for (int i = 0; i < 4; ++i)
                    Cb[(long long)(gr0 + i) * ldC + gc] = acc[m][n][i] + badd;
            }
    } else {
        float* slab = (float*)sm;   // [2][16][132] fp32
        const int wmi = wv >> 1;
#pragma unroll
        for (int m = 0; m < 4; ++m) {
            __syncthreads();
#pragma unroll
            for (int n = 0; n < 4; ++n) {
                const int col = wn + n * 16 + cc;
                const float badd = bias ? bias[bx * 128 + col] : 0.0f;
#pragma unroll
                for (int i = 0; i < 4; ++i)
                    slab[(wmi * 16 + cr + i) * 132 + col] = acc[m][n][i] + badd;
            }
            __syncthreads();
            if (WMODE == 1) {
#pragma unroll
                for (int it = 0; it < 2; ++it) {
                    const int e = it * 256 + t;
                    const int wq = e >> 8, cg = (e >> 4) & 15, fr = e & 15;
                    const float* sp = slab + (wq * 16 + fr) * 132 + cg * 8;
                    const int rIn = wq * 64 + m * 16 + fr;
                    const int ktO = bx * 4 + (cg >> 2);
                    const int gO = cg & 3;
                    const long long base =
                        ((long long)by * outNkt + ktO) * 4096 + (gO * 128 + rIn) * 8;
                    unsigned short h[8], l[8];
#pragma unroll
                    for (int j = 0; j < 8; ++j) splitbf(sp[j], h[j], l[j]);
                    uint4 hp, lp;
                    hp.x = h[0] | ((unsigned)h[1] << 16); hp.y = h[2] | ((unsigned)h[3] << 16);
                    hp.z = h[4] | ((unsigned)h[5] << 16); hp.w = h[6] | ((unsigned)h[7] << 16);
                    lp.x = l[0] | ((unsigned)l[1] << 16); lp.y = l[2] | ((unsigned)l[3] << 16);
                    lp.z = l[4] | ((unsigned)l[5] << 16); lp.w = l[6] | ((unsigned)l[7] << 16);
                    *(uint4*)(imgH + base) = hp;
                    *(uint4*)(imgL + base) = lp;
                }
            } else {    // WMODE 3: vT image (B-layout over C^T), h only
#pragma unroll
                for (int it = 0; it < 2; ++it) {
                    const int e = it * 256 + t;
                    const int wq = e >> 8, s8 = (e >> 7) & 1, dl = e & 127;
                    const int sG = by * 128 + wq * 64 + m * 16 + s8 * 8;
                    const int z = sG >> 11, sIn = sG & 2047;
                    const int ktO = sIn >> 5, gO = (sIn >> 3) & 3;
                    const long long base =
                        ((long long)(z * 8 + bx) * 64 + ktO) * 4096 + (gO * 128 + dl) * 8;
                    unsigned short h[8];
#pragma unroll
                    for (int j = 0; j < 8; ++j)
                        h[j] = rne_bf(slab[(wq * 16 + s8 * 8 + j) * 132 + dl]);
                    uint4 hp;
                    hp.x = h[0] | ((unsigned)h[1] << 16); hp.y = h[2] | ((unsigned)h[3] << 16);
                    hp.z = h[4] | ((unsigned)h[5] << 16); hp.w = h[6] | ((unsigned)h[7] << 16);
                    *(uint4*)(imgH + base) = hp;
                }
            }
        }
    }
}

// ---------------------------------------------------------------------------
// softmax over rows of energy, in place; also emits bf16 A-image of attn.
// ---------------------------------------------------------------------------
__global__ __launch_bounds__(256) void softmax_img(
    float* __restrict__ attn, const int* __restrict__ mask,
    unsigned short* __restrict__ img)
{
    const int row = blockIdx.x;
    const int q = row & (S_LEN - 1);
    const int t = threadIdx.x;
    const int lane = t & 63, wid = t >> 6;
    float* rp = attn + (long long)row * S_LEN;
    const int* mp = mask + (long long)q * S_LEN;

    const float4 e0 = *(const float4*)(rp + t * 8);
    const float4 e1 = *(const float4*)(rp + t * 8 + 4);
    const int4 ma = *(const int4*)(mp + t * 8);
    const int4 mb = *(const int4*)(mp + t * 8 + 4);
    float zv[8];
    zv[0] = ma.x ? -e0.x : 1e9f;
    zv[1] = ma.y ? -e0.y : 1e9f;
    zv[2] = ma.z ? -e0.z : 1e9f;
    zv[3] = ma.w ? -e0.w : 1e9f;
    zv[4] = mb.x ? -e1.x : 1e9f;
    zv[5] = mb.y ? -e1.y : 1e9f;
    zv[6] = mb.z ? -e1.z : 1e9f;
    zv[7] = mb.w ? -e1.w : 1e9f;
    float mx = zv[0];
#pragma unroll
    for (int j = 1; j < 8; ++j) mx = fmaxf(mx, zv[j]);
#pragma unroll
    for (int o = 32; o > 0; o >>= 1) mx = fmaxf(mx, __shfl_xor(mx, o));
    __shared__ float redm[4], reds[4];
    if (lane == 0) redm[wid] = mx;
    __syncthreads();
    mx = fmaxf(fmaxf(redm[0], redm[1]), fmaxf(redm[2], redm[3]));
    float s = 0.f;
#pragma unroll
    for (int j = 0; j < 8; ++j) { zv[j] = expf(zv[j] - mx); s += zv[j]; }
#pragma unroll
    for (int o = 32; o > 0; o >>= 1) s += __shfl_xor(s, o);
    if (lane == 0) reds[wid] = s;
    __syncthreads();
    s = reds[0] + reds[1] + reds[2] + reds[3];
    const float inv = 1.0f / s;
    float4 o0, o1;
    o0.x = zv[0] * inv; o0.y = zv[1] * inv; o0.z = zv[2] * inv; o0.w = zv[3] * inv;
    o1.x = zv[4] * inv; o1.y = zv[5] * inv; o1.z = zv[6] * inv; o1.w = zv[7] * inv;
    *(float4*)(rp + t * 8) = o0;
    *(float4*)(rp + t * 8 + 4) = o1;
    const int z = row >> 11, rb = (row >> 7) & 15;
    const int ktO = t >> 2, gO = t & 3, r = row & 127;
    const long long base = (((long long)(z * 16 + rb) * 64 + ktO) * 512 + gO * 128 + r) * 8;
    uint4 hp;
    hp.x = rne_bf(o0.x) | ((unsigned)rne_bf(o0.y) << 16);
    hp.y = rne_bf(o0.z) | ((unsigned)rne_bf(o0.w) << 16);
    hp.z = rne_bf(o1.x) | ((unsigned)rne_bf(o1.y) << 16);
    hp.w = rne_bf(o1.z) | ((unsigned)rne_bf(o1.w) << 16);
    *(uint4*)(img + base) = hp;
}

// WqT[j][i] = Wq[i][j]  (1024x1024) — fallback path only
__global__ void transpose1024(const float* __restrict__ in, float* __restrict__ out)
{
    __shared__ float tile[32][33];
    const int bx = blockIdx.x << 5, by = blockIdx.y << 5;
    const int tx = threadIdx.x, ty = threadIdx.y;
#pragma unroll
    for (int i = 0; i < 4; ++i)
        tile[ty + 8 * i][tx] = in[(long long)(by + ty + 8 * i) * E_DIM + bx + tx];
    __syncthreads();
#pragma unroll
    for (int i = 0; i < 4; ++i)
        out[(long long)(bx + ty + 8 * i) * E_DIM + by + tx] = tile[tx][ty + 8 * i];
}

// t1[i] = dot(bq, We[i,:])  (= We . bq)
__global__ __launch_bounds__(256) void bias_c_kernel(
    const float* __restrict__ We, const float* __restrict__ bq, float* __restrict__ c)
{
    const int i = blockIdx.x;
    const int t = threadIdx.x;
    float s = 0.f;
    for (int d = t; d < E_DIM; d += 256) s += bq[d] * We[(long long)i * E_DIM + d];
#pragma unroll
    for (int o = 32; o > 0; o >>= 1) s += __shfl_xor(s, o);
    __shared__ float red[4];
    if ((t & 63) == 0) red[t >> 6] = s;
    __syncthreads();
    if (t == 0) c[i] = red[0] + red[1] + red[2] + red[3];
}

// ---------------------------------------------------------------------------
// FALLBACK path (round-1 proven), used only if ws_size is too small.
// ---------------------------------------------------------------------------
template <bool SPLIT, int WMODE>
__global__ __launch_bounds__(256) void gemm_split(
    const float* __restrict__ A, const float* __restrict__ B,
    float* __restrict__ C, const float* __restrict__ bias,
    int M, int N, int K,
    long long bsA, long long bsB, long long bsC)
{
    extern __shared__ unsigned short sm[];
    unsigned short* sAh = sm;
    unsigned short* sBh = sm + 5120;
    unsigned short* sAl = sm + 10240;
    unsigned short* sBl = sm + 15360;

    const int t = threadIdx.x;
    const int z = blockIdx.z;
    const float* Ab = A + (long long)z * bsA + (long long)blockIdx.y * 128 * K;
    const float* Bb = B + (long long)z * bsB + (long long)blockIdx.x * 128 * K;

    const int wv = t >> 6;
    const int lane = t & 63;
    const int wm = (wv >> 1) << 6;
    const int wn = (wv & 1) << 6;
    const int lr = lane & 15;
    const int ko = (lane >> 4) << 3;

    f32x4 acc[4][4] = {};

    for (int k0 = 0; k0 < K; k0 += 32) {
        __syncthreads();
#pragma unroll
        for (int i = 0; i < 4; ++i) {
            const int f = t + (i << 8);
            const int row = f >> 3;
            const int c4 = (f & 7) << 2;
            const float4 av = *(const float4*)(Ab + (long long)row * K + k0 + c4);
            const float4 bv = *(const float4*)(Bb + (long long)row * K + k0 + c4);
            if (SPLIT) {
                unsigned short h0, h1, h2, h3, l0, l1, l2, l3;
                splitbf(av.x, h0, l0); splitbf(av.y, h1, l1);
                splitbf(av.z, h2, l2); splitbf(av.w, h3, l3);
                uint2 hp, lp;
                hp.x = (unsigned)h0 | ((unsigned)h1 << 16);
                hp.y = (unsigned)h2 | ((unsigned)h3 << 16);
                lp.x = (unsigned)l0 | ((unsigned)l1 << 16);
                lp.y = (unsigned)l2 | ((unsigned)l3 << 16);
                *(uint2*)(sAh + row * 40 + c4) = hp;
                *(uint2*)(sAl + row * 40 + c4) = lp;
                splitbf(bv.x, h0, l0); splitbf(bv.y, h1, l1);
                splitbf(bv.z, h2, l2); splitbf(bv.w, h3, l3);
                hp.x = (unsigned)h0 | ((unsigned)h1 << 16);
                hp.y = (unsigned)h2 | ((unsigned)h3 << 16);
                lp.x = (unsigned)l0 | ((unsigned)l1 << 16);
                lp.y = (unsigned)l2 | ((unsigned)l3 << 16);
                *(uint2*)(sBh + row * 40 + c4) = hp;
                *(uint2*)(sBl + row * 40 + c4) = lp;
            } else {
                uint2 hp;
                hp.x = (unsigned)rne_bf(av.x) | ((unsigned)rne_bf(av.y) << 16);
                hp.y = (unsigned)rne_bf(av.z) | ((unsigned)rne_bf(av.w) << 16);
                *(uint2*)(sAh + row * 40 + c4) = hp;
                hp.x = (unsigned)rne_bf(bv.x) | ((unsigned)rne_bf(bv.y) << 16);
                hp.y = (unsigned)rne_bf(bv.z) | ((unsigned)rne_bf(bv.w) << 16);
                *(uint2*)(sBh + row * 40 + c4) = hp;
            }
        }
        __syncthreads();
        short8 ah[4], bh[4], al[4], bl[4];
#pragma unroll
        for (int m = 0; m < 4; ++m)
            ah[m] = *(const short8*)(sAh + (wm + m * 16 + lr) * 40 + ko);
#pragma unroll
        for (int n = 0; n < 4; ++n)
            bh[n] = *(const short8*)(sBh + (wn + n * 16 + lr) * 40 + ko);
        if (SPLIT) {
#pragma unroll
            for (int m = 0; m < 4; ++m)
                al[m] = *(const short8*)(sAl + (wm + m * 16 + lr) * 40 + ko);
#pragma unroll
            for (int n = 0; n < 4; ++n)
                bl[n] = *(const short8*)(sBl + (wn + n * 16 + lr) * 40 + ko);
        }
#pragma unroll
        for (int m = 0; m < 4; ++m) {
#pragma unroll
            for (int n = 0; n < 4; ++n) {
                acc[m][n] = __builtin_amdgcn_mfma_f32_16x16x32_bf16(ah[m], bh[n], acc[m][n], 0, 0, 0);
                if (SPLIT) {
                    acc[m][n] = __builtin_amdgcn_mfma_f32_16x16x32_bf16(ah[m], bl[n], acc[m][n], 0, 0, 0);
                    acc[m][n] = __builtin_amdgcn_mfma_f32_16x16x32_bf16(al[m], bh[n], acc[m][n], 0, 0, 0);
                }
            }
        }
    }

    const int cr = (lane >> 4) << 2;
    const int cc = lane & 15;
    float* Cb = C + (long long)z * bsC;
#pragma unroll
    for (int m = 0; m < 4; ++m) {
#pragma unroll
        for (int n = 0; n < 4; ++n) {
            const int gc = blockIdx.x * 128 + wn + n * 16 + cc;
            const float badd = bias ? bias[gc] : 0.0f;
            const int gr0 = blockIdx.y * 128 + wm + m * 16 + cr;
#pragma unroll
            for (int i = 0; i < 4; ++i) {
                const float val = acc[m][n][i] + badd;
                if (WMODE == 0) {
                    Cb[(long long)(gr0 + i) * N + gc] = val;
                } else {
                    const int r = gr0 + i;
                    Cb[(long long)(r >> 11) * ((long long)N * 2048) +
                       (long long)gc * 2048 + (r & 2047)] = val;
                }
            }
        }
    }
}

__global__ __launch_bounds__(256) void softmax_rows(
    float* __restrict__ attn, const int* __restrict__ mask)
{
    const int row = blockIdx.x;
    const int q = row & (S_LEN - 1);
    const int t = threadIdx.x;
    const int lane = t & 63, wid = t >> 6;
    float* rp = attn + (long long)row * S_LEN;
    const int* mp = mask + (long long)q * S_LEN;

    float zv[8];
    float mx = -3.4e38f;
#pragma unroll
    for (int j = 0; j < 8; ++j) {
        const int idx = t + (j << 8);
        const float e = rp[idx];
        const int mv = mp[idx];
        const float zz = (mv != 0) ? -e : 1e9f;
        zv[j] = zz;
        mx = fmaxf(mx, zz);
    }
#pragma unroll
    for (int o = 32; o > 0; o >>= 1) mx = fmaxf(mx, __shfl_xor(mx, o));
    __shared__ float redm[4], reds[4];
    if (lane == 0) redm[wid] = mx;
    __syncthreads();
    mx = fmaxf(fmaxf(redm[0], redm[1]), fmaxf(redm[2], redm[3]));

    float s = 0.f;
#pragma unroll
    for (int j = 0; j < 8; ++j) { zv[j] = expf(zv[j] - mx); s += zv[j]; }
#pragma unroll
    for (int o = 32; o > 0; o >>= 1) s += __shfl_xor(s, o);
    if (lane == 0) reds[wid] = s;
    __syncthreads();
    s = reds[0] + reds[1] + reds[2] + reds[3];
    const float inv = 1.0f / s;
#pragma unroll
    for (int j = 0; j < 8; ++j) rp[t + (j << 8)] = zv[j] * inv;
}

// ---------------------------------------------------------------------------
extern "C" void kernel_launch(void* const* d_in, const int* in_sizes, int n_in,
                              void* d_out, int out_size, void* d_ws, size_t ws_size,
                              hipStream_t stream)
{
    const float* query = (const float*)d_in[0];
    const float* key   = (const float*)d_in[1];
    const float* value = (const float*)d_in[2];
    const int*   mask  = (const int*)d_in[3];
    const float* Wq    = (const float*)d_in[4];
    const float* bq    = (const float*)d_in[5];
    const float* Wk    = (const float*)d_in[6];
    const float* bk    = (const float*)d_in[7];
    const float* Wv    = (const float*)d_in[8];
    const float* bv    = (const float*)d_in[9];
    const float* We    = (const float*)d_in[10];

    float* out  = (float*)d_out;
    float* attn = out + (long long)NB * S_LEN * E_DIM;

    // ---------------- ws layout (byte offsets) ----------------
    const size_t oT1   = 0;
    const size_t oW    = 4096;
    const size_t oR    = 8192;
    const size_t oWts  = 131072;                  // 9 x 2MB weight-image slots
    const size_t oWqTH = oWts + 0 * (2u << 20);
    const size_t oWqTL = oWts + 1 * (2u << 20);
    const size_t oWkTH = oWts + 2 * (2u << 20);
    const size_t oWkTL = oWts + 3 * (2u << 20);
    const size_t oWeH  = oWts + 4 * (2u << 20);   // -> GTH after PT GEMM
    const size_t oWeL  = oWts + 5 * (2u << 20);   // -> GTL
    const size_t oWvH  = oWts + 6 * (2u << 20);
    const size_t oPTH  = oWts + 7 * (2u << 20);
    const size_t oPTL  = oWts + 8 * (2u << 20);
    const size_t oBig1 = oWts + 9 * (2u << 20);   // qryH|qryL -> attnH (64MB)
    const size_t oBig2 = oBig1 + (64u << 20);     // keyH|keyL
    const size_t oBig3 = oBig2 + (64u << 20);     // qgH|qgL -> vTH|valH
    const size_t NEED  = oBig3 + (64u << 20);

    char* wsb = (char*)d_ws;

    if (ws_size >= NEED) {
        float* t1 = (float*)(wsb + oT1);
        float* wv = (float*)(wsb + oW);
        float* rv = (float*)(wsb + oR);
        unsigned short* WqTH = (unsigned short*)(wsb + oWqTH);
        unsigned short* WqTL = (unsigned short*)(wsb + oWqTL);
        unsigned short* WkTH = (unsigned short*)(wsb + oWkTH);
        unsigned short* WkTL = (unsigned short*)(wsb + oWkTL);
        unsigned short* WeH  = (unsigned short*)(wsb + oWeH);
        unsigned short* WeL  = (unsigned short*)(wsb + oWeL);
        unsigned short* GTH  = (unsigned short*)(wsb + oWeH);   // alias (We dead)
        unsigned short* GTL  = (unsigned short*)(wsb + oWeL);   // alias
        unsigned short* WvH  = (unsigned short*)(wsb + oWvH);
        unsigned short* PTH  = (unsigned short*)(wsb + oPTH);
        unsigned short* PTL  = (unsigned short*)(wsb + oPTL);
        unsigned short* qryH = (unsigned short*)(wsb + oBig1);
        unsigned short* qryL = (unsigned short*)(wsb + oBig1 + (32u << 20));
        unsigned short* attnH = (unsigned short*)(wsb + oBig1);           // alias
        unsigned short* keyH = (unsigned short*)(wsb + oBig2);
        unsigned short* keyL = (unsigned short*)(wsb + oBig2 + (32u << 20));
        unsigned short* qgH  = (unsigned short*)(wsb + oBig3);
        unsigned short* qgL  = (unsigned short*)(wsb + oBig3 + (32u << 20));
        unsigned short* vTH  = (unsigned short*)(wsb + oBig3);            // alias
        unsigned short* valH = (unsigned short*)(wsb + oBig3 + (32u << 20));

        // bias path: t1 = We.bq ; w = Wk^T.t1 (atomic, pre-zeroed) ; r = key.w
        hipMemsetAsync(wv, 0, 4096, stream);
        bias_c_kernel<<<1024, 256, 0, stream>>>(We, bq, t1);
        wvec2_kernel<<<64, 256, 0, stream>>>(Wk, t1, wv);
        rvec_kernel<<<NB * S_LEN, 256, 0, stream>>>(key, wv, rv);

        // weight images: Wq^T,Wk^T (merged), We, Wv
        conv_imgT2<<<dim3(32, 8, 2), 256, 0, stream>>>(
            Wq, Wk, WqTH, WqTL, WkTH, WkTL, 32);
        conv_img<true><<<dim3(32, 8), 256, 0, stream>>>(We, WeH, WeL, 1024, 32);
        conv_img<false><<<dim3(32, 8), 256, 0, stream>>>(Wv, WvH, nullptr, 1024, 32);
        // input images: query + key merged
        conv_img2<<<dim3(32, 128, 2), 256, 0, stream>>>(
            query, key, qryH, qryL, keyH, keyL, 32);

        // PT = Wq^T @ We^T  (A=WqT, B=We)  -> PTH/PTL
        gemm_img<3, 1><<<dim3(8, 8, 1), 256, 49152, stream>>>(
            WqTH, WqTL, WeH, WeL, nullptr, nullptr, PTH, PTL, 0, 0, 32, 0, 0, 32);
        // GT = Wk^T @ PT^T = G^T  (A=WkT, B=PT) -> GTH/GTL (over dead We slots)
        gemm_img<3, 1><<<dim3(8, 8, 1), 256, 49152, stream>>>(
            WkTH, WkTL, PTH, PTL, nullptr, nullptr, GTH, GTL, 0, 0, 32, 0, 0, 32);
        // qg = query @ GT^T = query.G  -> qg images in Big3
        gemm_img<3, 1><<<dim3(8, 128, 1), 256, 49152, stream>>>(
            qryH, qryL, GTH, GTL, nullptr, nullptr, qgH, qgL, 0, 0, 32, 0, 0, 32);
        // energy = qg @ key^T + r[col]  -> attn region (fp32 scratch)
        gemm_e3<<<dim3(16, 8, NB), 512, 0, stream>>>(
            qgH, qgL, keyH, keyL, rv, attn,
            2048, (long long)S_LEN * S_LEN, 32, 16, 16);
        // value image (over dead qgL), then v-proj -> vT image (over dead qgH)
        conv_img<false><<<dim3(32, 128), 256, 0, stream>>>(value, valH, nullptr, 1024, 32);
        gemm_img<1, 3><<<dim3(8, 128, 1), 256, 49152, stream>>>(
            valH, nullptr, WvH, nullptr, nullptr, bv, vTH, nullptr, 0, 0, 32, 0, 0, 0);
        // softmax in place + attn bf16 image (over dead qry images)
        softmax_img<<<NB * S_LEN, 256, 0, stream>>>(attn, mask, attnH);
        // out = attn @ v per batch
        gemm_big<1><<<dim3(8, 8, NB), 512, 0, stream>>>(
            attnH, nullptr, vTH, nullptr, out, nullptr,
            1024, (long long)S_LEN * E_DIM, 64, 16, 8);
    } else {
        float* ws   = (float*)d_ws;
        float* WqT  = ws;
        float* P    = WqT + 1048576;
        float* cvec = P + 1048576;
        float* kbuf = cvec + 1024;
        float* qw   = kbuf + 16777216;
        float* vT   = qw + 16777216;
        const size_t need_old = (size_t)(1048576 * 2 + 1024 + 16777216 * 3) * 4;
        if (ws_size < need_old) return;

        transpose1024<<<dim3(32, 32), dim3(32, 8), 0, stream>>>(Wq, WqT);
        bias_c_kernel<<<1024, 256, 0, stream>>>(We, bq, cvec);
        gemm_split<true, 0><<<dim3(8, 8, 1), 256, 40960, stream>>>(
            We, WqT, P, nullptr, 1024, 1024, 1024, 0, 0, 0);
        gemm_split<true, 0><<<dim3(8, 128, 1), 256, 40960, stream>>>(
            key, Wk, kbuf, bk, 16384, 1024, 1024, 0, 0, 0);
        gemm_split<false, 1><<<dim3(8, 128, 1), 256, 20480, stream>>>(
            value, Wv, vT, bv, 16384, 1024, 1024, 0, 0, 0);
        gemm_split<true, 0><<<dim3(8, 128, 1), 256, 40960, stream>>>(
            query, P, qw, cvec, 16384, 1024, 1024, 0, 0, 0);
        gemm_split<true, 0><<<dim3(16, 16, NB), 256, 40960, stream>>>(
            qw, kbuf, attn, nullptr, 2048, 2048, 1024,
            (long long)S_LEN * E_DIM, (long long)S_LEN * E_DIM, (long long)S_LEN * S_LEN);
        softmax_rows<<<NB * S_LEN, 256, 0, stream>>>(attn, mask);
        gemm_split<false, 0><<<dim3(8, 16, NB), 256, 20480, stream>>>(
            attn, vT, out, nullptr, 2048, 1024, 2048,
            (long long)S_LEN * S_LEN, (long long)E_DIM * S_LEN, (long long)S_LEN * E_DIM);
    }

    (void)in_sizes; (void)n_in; (void)out_size;
}